// Round 8
// baseline (660.591 us; speedup 1.0000x reference)
//
#include <hip/hip_runtime.h>
#include <stdint.h>

// LRU forward: y = Re(scan(lam, gamma*(x@B^T)) @ C^T) + x @ D^T
// Round 8: A-operand (states/x) in fragment-tiled layout, loaded global->VGPR
// fully coalesced (1KB/wave-load, 2-deep per-wave prefetch, no barrier convoy).
// B (weights) stays DMA->LDS (quad-XOR swizzle, 0 conflicts), double-buffered
// with counted vmcnt. LDS 32KB -> better residency. setprio around MFMA (T5).

#define BSZ   8
#define TLEN  4096
#define DIN   1024
#define DOUT  1024
#define NST   512
#define M_TOT (BSZ * TLEN)   // 32768
#define NC    32
#define CL    128
#define PL    4096           // LDS B-plane: 128 rows x 32 shorts (8 KB)

typedef __attribute__((ext_vector_type(8))) short bf16x8;
typedef __attribute__((ext_vector_type(4))) float f32x4;

// ---- bf16 helpers -------------------------------------------------------------------------
__device__ __forceinline__ float s2f(short s) {
  unsigned v = ((unsigned)(unsigned short)s) << 16;
  return __builtin_bit_cast(float, v);
}
__device__ __forceinline__ short f2s_rne(float f) {
  unsigned u = __builtin_bit_cast(unsigned, f);
  unsigned r = (u + 0x7FFFu + ((u >> 16) & 1u)) >> 16;
  return (short)r;
}
// h = truncated-bf16(f) (residual exactly representable), l = RNE(f - h)
__device__ __forceinline__ void split(float f, short& h, short& l) {
  const unsigned u = __builtin_bit_cast(unsigned, f);
  h = (short)(u >> 16);
  const float fh = __builtin_bit_cast(float, u & 0xFFFF0000u);
  l = f2s_rne(f - fh);
}
__device__ __forceinline__ void split8(const float4 v0, const float4 v1,
                                       bf16x8& hv, bf16x8& lv) {
  const float f[8] = {v0.x, v0.y, v0.z, v0.w, v1.x, v1.y, v1.z, v1.w};
  #pragma unroll
  for (int j = 0; j < 8; ++j) { short hh, ll; split(f[j], hh, ll); hv[j] = hh; lv[j] = ll; }
}

// ---- async global->LDS, 16B per lane ------------------------------------------------------
__device__ __forceinline__ void gload16(const short* g, short* l) {
  __builtin_amdgcn_global_load_lds(
      (const __attribute__((address_space(1))) void*)g,
      (__attribute__((address_space(3))) void*)l, 16, 0, 0);
}

// Tiled A-plane layout L(K): element (m,k) at
//   (m>>4)*16K + (k>>5)*512 + (((k>>3)&3)*16 + (m&15))*8 + (k&7)
// A wave's MFMA A-fragment for (m-tile T, k-step G) = shorts [T*16K + G*512 + lane*8, +8)
// -> one fully-coalesced 1KB global load per (tile, plane).

// ---- stage one K-step of B weight planes into LDS (DMA, quad-XOR source swizzle) ----------
template<int NBP>
__device__ __forceinline__ void stage_B(const short* __restrict__ Bph,
    const short* __restrict__ Bpl, const int ldb, const int n0, const int k0,
    short* lbuf, const int w, const int lane)
{
  const int q  = (lane & 3) ^ ((lane >> 3) & 3);
  const int gr = lane >> 2;
  #pragma unroll
  for (int j = 0; j < NBP * 2; ++j) {
    const int L = w * (NBP * 2) + j;
    const int p = L >> 3, c = L & 7;
    const short* g = (p == 0) ? Bph : Bpl;
    gload16(g + (size_t)(n0 + c * 16 + gr) * ldb + k0 + q * 8, lbuf + p * PL + c * 512);
  }
}

// ---- pipelined GEMM: A direct-from-tiled-global, B via LDS. NP=4: 3 MFMA, NP=3: 2 MFMA ----
template<int NT, int NP>
__device__ __forceinline__ void gemm_dir(
    const short* __restrict__ Aph, const short* __restrict__ Apl, const int K,
    const short* __restrict__ Bph, const short* __restrict__ Bpl, const int ldb,
    const int m0, const int n0, const int tid,
    f32x4 (&acc)[4][4], short* lds)
{
  constexpr int NBP = (NP == 4) ? 2 : 1;
  constexpr int WN  = 16 + NBP * 2;        // steady-state counted vmcnt
  const int lane = tid & 63, w = tid >> 6, wm = w >> 1, wn = w & 1;
  const int lr = lane & 15, kg = lane >> 4;
  const int qo = (kg ^ ((lr >> 1) & 3)) * 8;
  const size_t TS = (size_t)K * 16;        // shorts per m-tile
  const short* Abh = Aph + ((size_t)(m0 >> 4) + (size_t)wm * 4) * TS + (size_t)lane * 8;
  const short* Abl = Apl + ((size_t)(m0 >> 4) + (size_t)wm * 4) * TS + (size_t)lane * 8;
  short* buf0 = lds;
  short* buf1 = lds + NBP * PL;

  bf16x8 ah0[4], al0[4], ah1[4], al1[4];

  // prologue: B(0), B(1) DMA; A(0), A(1) -> regs
  stage_B<NBP>(Bph, Bpl, ldb, n0, 0,  buf0, w, lane);
  stage_B<NBP>(Bph, Bpl, ldb, n0, 32, buf1, w, lane);
  #pragma unroll
  for (int mi = 0; mi < 4; ++mi) {
    ah0[mi] = *(const bf16x8*)(Abh + (size_t)mi * TS);
    al0[mi] = *(const bf16x8*)(Abl + (size_t)mi * TS);
    ah1[mi] = *(const bf16x8*)(Abh + (size_t)mi * TS + 512);
    al1[mi] = *(const bf16x8*)(Abl + (size_t)mi * TS + 512);
  }

  for (int kk = 0; kk < NT; kk += 2) {
    // ================= even step kk (buf0 / set0) =================
    asm volatile("s_waitcnt vmcnt(%0)" :: "i"(WN) : "memory");
    __builtin_amdgcn_s_barrier();
    bf16x8 bh[4], bl[4];
    #pragma unroll
    for (int ni = 0; ni < 4; ++ni) {
      const int co = (wn * 64 + ni * 16 + lr) * 32 + qo;
      bh[ni] = *(const bf16x8*)&buf0[co];
      if constexpr (NP == 4) bl[ni] = *(const bf16x8*)&buf0[PL + co];
    }
    asm volatile("s_waitcnt lgkmcnt(0)" ::: "memory");
    __builtin_amdgcn_s_barrier();
    if (kk + 2 < NT) stage_B<NBP>(Bph, Bpl, ldb, n0, (kk + 2) * 32, buf0, w, lane);
    __builtin_amdgcn_s_setprio(1);
    #pragma unroll
    for (int ni = 0; ni < 4; ++ni)
      #pragma unroll
      for (int mi = 0; mi < 4; ++mi) {
        acc[mi][ni] = __builtin_amdgcn_mfma_f32_16x16x32_bf16(ah0[mi], bh[ni], acc[mi][ni], 0, 0, 0);
        acc[mi][ni] = __builtin_amdgcn_mfma_f32_16x16x32_bf16(al0[mi], bh[ni], acc[mi][ni], 0, 0, 0);
        if constexpr (NP == 4)
          acc[mi][ni] = __builtin_amdgcn_mfma_f32_16x16x32_bf16(ah0[mi], bl[ni], acc[mi][ni], 0, 0, 0);
      }
    __builtin_amdgcn_s_setprio(0);
    if (kk + 2 < NT) {
      #pragma unroll
      for (int mi = 0; mi < 4; ++mi) {
        ah0[mi] = *(const bf16x8*)(Abh + (size_t)mi * TS + (size_t)(kk + 2) * 512);
        al0[mi] = *(const bf16x8*)(Abl + (size_t)mi * TS + (size_t)(kk + 2) * 512);
      }
    }
    // ================= odd step kk+1 (buf1 / set1) =================
    if (kk + 2 < NT) asm volatile("s_waitcnt vmcnt(%0)" :: "i"(WN) : "memory");
    else             asm volatile("s_waitcnt vmcnt(8)" ::: "memory");
    __builtin_amdgcn_s_barrier();
    #pragma unroll
    for (int ni = 0; ni < 4; ++ni) {
      const int co = (wn * 64 + ni * 16 + lr) * 32 + qo;
      bh[ni] = *(const bf16x8*)&buf1[co];
      if constexpr (NP == 4) bl[ni] = *(const bf16x8*)&buf1[PL + co];
    }
    asm volatile("s_waitcnt lgkmcnt(0)" ::: "memory");
    __builtin_amdgcn_s_barrier();
    if (kk + 3 < NT) stage_B<NBP>(Bph, Bpl, ldb, n0, (kk + 3) * 32, buf1, w, lane);
    __builtin_amdgcn_s_setprio(1);
    #pragma unroll
    for (int ni = 0; ni < 4; ++ni)
      #pragma unroll
      for (int mi = 0; mi < 4; ++mi) {
        acc[mi][ni] = __builtin_amdgcn_mfma_f32_16x16x32_bf16(ah1[mi], bh[ni], acc[mi][ni], 0, 0, 0);
        acc[mi][ni] = __builtin_amdgcn_mfma_f32_16x16x32_bf16(al1[mi], bh[ni], acc[mi][ni], 0, 0, 0);
        if constexpr (NP == 4)
          acc[mi][ni] = __builtin_amdgcn_mfma_f32_16x16x32_bf16(ah1[mi], bl[ni], acc[mi][ni], 0, 0, 0);
      }
    __builtin_amdgcn_s_setprio(0);
    if (kk + 3 < NT) {
      #pragma unroll
      for (int mi = 0; mi < 4; ++mi) {
        ah1[mi] = *(const bf16x8*)(Abh + (size_t)mi * TS + (size_t)(kk + 3) * 512);
        al1[mi] = *(const bf16x8*)(Abl + (size_t)mi * TS + (size_t)(kk + 3) * 512);
      }
    }
  }
}

// ---- x-fallback helpers (x fp32 row-major, reg-split, swizzled ds_write) ------------------
__device__ __forceinline__ void stageAx(const float4 (&pa)[4], short* Ah, short* Al,
                                        const int r, const int kh)
{
  bf16x8 h0, l0, h1, l1;
  split8(pa[0], pa[1], h0, l0);
  split8(pa[2], pa[3], h1, l1);
  const int f  = (r >> 1) & 3;
  const int q0 = ((2 * kh) ^ f) * 8, q1 = ((2 * kh + 1) ^ f) * 8;
  *(bf16x8*)&Ah[r * 32 + q0] = h0;  *(bf16x8*)&Ah[r * 32 + q1] = h1;
  *(bf16x8*)&Al[r * 32 + q0] = l0;  *(bf16x8*)&Al[r * 32 + q1] = l1;
}

__device__ __forceinline__ void gemm_fb(
    const float* __restrict__ Af, const short* __restrict__ Bw,
    const int lda, const int ldb, const int K, const int m0, const int n0, const int tid,
    f32x4 (&acc)[4][4], short* lds)    // planes: Ah@0, Al@PL, Bw@2*PL
{
  const int lane = tid & 63, w = tid >> 6, wm = w >> 1, wn = w & 1;
  const int r = tid & 127, kh = tid >> 7;
  short *LAh = lds, *LAl = lds + PL, *LB = lds + 2 * PL;
  float4 pa[4];
  {
    const float* p = Af + (size_t)(m0 + r) * lda + kh * 16;
    #pragma unroll
    for (int i = 0; i < 4; ++i) pa[i] = *(const float4*)(p + 4 * i);
  }
  for (int k0 = 0; k0 < K; k0 += 32) {
    __syncthreads();
    stageAx(pa, LAh, LAl, r, kh);
    if (w >= 2) {
      const int q = (lane & 3) ^ ((lane >> 3) & 3);
      const int gr = lane >> 2;
      const int c0 = (w & 1) * 4;
      #pragma unroll
      for (int i = 0; i < 4; ++i)
        gload16(Bw + (size_t)(n0 + (c0 + i) * 16 + gr) * ldb + k0 + q * 8,
                LB + (c0 + i) * 512);
    }
    __syncthreads();
    if (k0 + 32 < K) {
      const float* p = Af + (size_t)(m0 + r) * lda + (k0 + 32) + kh * 16;
      #pragma unroll
      for (int i = 0; i < 4; ++i) pa[i] = *(const float4*)(p + 4 * i);
    }
    const int lr = lane & 15, kg = lane >> 4;
    const int qo = (kg ^ ((lr >> 1) & 3)) * 8;
    bf16x8 ah[4], al[4], bh[4];
    #pragma unroll
    for (int mi = 0; mi < 4; ++mi) {
      const int ro = (wm * 64 + mi * 16 + lr) * 32 + qo;
      ah[mi] = *(const bf16x8*)&LAh[ro];
      al[mi] = *(const bf16x8*)&LAl[ro];
    }
    #pragma unroll
    for (int ni = 0; ni < 4; ++ni)
      bh[ni] = *(const bf16x8*)&LB[(wn * 64 + ni * 16 + lr) * 32 + qo];
    #pragma unroll
    for (int ni = 0; ni < 4; ++ni)
      #pragma unroll
      for (int mi = 0; mi < 4; ++mi) {
        acc[mi][ni] = __builtin_amdgcn_mfma_f32_16x16x32_bf16(ah[mi], bh[ni], acc[mi][ni], 0, 0, 0);
        acc[mi][ni] = __builtin_amdgcn_mfma_f32_16x16x32_bf16(al[mi], bh[ni], acc[mi][ni], 0, 0, 0);
      }
  }
  __syncthreads();
}

// ---- XCD-locality block mapping (verified r6: FETCH -70%) ---------------------------------
__device__ __forceinline__ void map_mn(const int bid, int& mb, int& nb) {
  const int xcd = bid & 7;
  const int j   = bid >> 3;
  mb = xcd * 32 + (j >> 3);
  nb = j & 7;
}

// ---- weight pre-split / pre-round (row-major, for DMA staging) ----------------------------
__global__ __launch_bounds__(256) void wsplit_k(const float* __restrict__ src,
    short* __restrict__ h, short* __restrict__ l, const int n4, const float sgn)
{
  const int i = blockIdx.x * 256 + threadIdx.x;
  if (i >= n4) return;
  const float4 v = ((const float4*)src)[i];
  const float f[4] = {sgn * v.x, sgn * v.y, sgn * v.z, sgn * v.w};
  short4 hv, lv;
  split(f[0], hv.x, lv.x); split(f[1], hv.y, lv.y);
  split(f[2], hv.z, lv.z); split(f[3], hv.w, lv.w);
  ((short4*)h)[i] = hv;
  ((short4*)l)[i] = lv;
}
__global__ __launch_bounds__(256) void wround_k(const float* __restrict__ src,
    short* __restrict__ h, const int n4)
{
  const int i = blockIdx.x * 256 + threadIdx.x;
  if (i >= n4) return;
  const float4 v = ((const float4*)src)[i];
  short4 hv;
  hv.x = f2s_rne(v.x); hv.y = f2s_rne(v.y); hv.z = f2s_rne(v.z); hv.w = f2s_rne(v.w);
  ((short4*)h)[i] = hv;
}

// ---- x pre-split into TILED L(1024) planes (coalesced 16B writes) -------------------------
__global__ __launch_bounds__(256) void wsplit_xt(const float* __restrict__ src,
    short* __restrict__ h, short* __restrict__ l)
{
  const int cI = blockIdx.x * 256 + threadIdx.x;      // chunk id (8 shorts each)
  const int T   = cI >> 11;                           // m-tile (2048 chunks per tile)
  const int rem = cI & 2047;
  const int G   = rem >> 6;                           // k-group of 32
  const int ln  = rem & 63;                           // lane slot
  const int m = T * 16 + (ln & 15);
  const int k = G * 32 + (ln >> 4) * 8;
  const float4 v0 = *(const float4*)&src[(size_t)m * DIN + k];
  const float4 v1 = *(const float4*)&src[(size_t)m * DIN + k + 4];
  bf16x8 hv, lv;
  split8(v0, v1, hv, lv);
  *(bf16x8*)&h[(size_t)cI * 8] = hv;
  *(bf16x8*)&l[(size_t)cI * 8] = lv;
}

// ---- kernel 1: Bu planes (TILED L(512)) = split(gamma * (x @ [Bre|Bim]^T)) ----------------
template<bool XAG>
__global__ __launch_bounds__(256, 2) void bu_mfma(
    const float* __restrict__ x, const short* __restrict__ xh, const short* __restrict__ xl,
    const short* __restrict__ Brw, const short* __restrict__ Biw,
    const float* __restrict__ gamma,
    short* __restrict__ re_h, short* __restrict__ re_l,
    short* __restrict__ im_h, short* __restrict__ im_l)
{
  __shared__ short lds[12288];             // 24 KB (gemm_dir uses 16 KB, fb uses 24 KB)
  f32x4 acc[4][4] = {};
  const int tid = threadIdx.x;
  int mb, nbk;
  map_mn(blockIdx.x, mb, nbk);
  const int m0  = mb * 128;
  const int n0s = nbk * 128;
  const bool re = (n0s < NST);
  const int nb0 = n0s & (NST - 1);
  const short* Bw = re ? Brw : Biw;

  if constexpr (XAG)
    gemm_dir<32, 3>(xh, xl, DIN, Bw, nullptr, DIN, m0, nb0, tid, acc, lds);
  else
    gemm_fb(x, Bw, DIN, DIN, DIN, m0, nb0, tid, acc, lds);

  short* Hp = re ? re_h : im_h;
  short* Lp = re ? re_l : im_l;
  const int lane = tid & 63, w = tid >> 6, wm = w >> 1, wn = w & 1;
  const int lr = lane & 15, lq = lane >> 4;
  #pragma unroll
  for (int ni = 0; ni < 4; ++ni) {
    const int nb = nb0 + wn * 64 + ni * 16 + lr;
    const float g = gamma[nb];
    const size_t cn = ((size_t)(nb >> 5) << 9) + (size_t)(((nb >> 3) & 3) << 7) + (nb & 7);
    #pragma unroll
    for (int mi = 0; mi < 4; ++mi) {
      const size_t tb = (size_t)((m0 >> 4) + wm * 4 + mi) * 8192 + cn;
      #pragma unroll
      for (int j = 0; j < 4; ++j) {
        const size_t idx = tb + (size_t)(lq * 4 + j) * 8;
        short hh, ll;
        split(acc[mi][ni][j] * g, hh, ll);
        Hp[idx] = hh;
        Lp[idx] = ll;
      }
    }
  }
}

// ---- scan params --------------------------------------------------------------------------
__global__ void params_k(const float* __restrict__ nulog, const float* __restrict__ thlog,
                         const float* __restrict__ glog,
                         float2* __restrict__ lam, float2* __restrict__ lamL,
                         float* __restrict__ gamma)
{
  const int n = blockIdx.x * 256 + threadIdx.x;
  if (n >= NST) return;
  const float nu = expf(nulog[n]);
  const float th = expf(thlog[n]);
  const float mod = expf(-nu);
  float s, c;
  sincosf(th, &s, &c);
  lam[n] = make_float2(mod * c, mod * s);
  const float modL = expf(-(float)CL * nu);
  float sL, cL;
  sincosf((float)CL * th, &sL, &cL);
  lamL[n] = make_float2(modL * cL, modL * sL);
  gamma[n] = expf(glog[n]);
}

// ---- scan phase 1 (tiled layout) ----------------------------------------------------------
__global__ __launch_bounds__(256) void scan_partial(
    const short* __restrict__ re_h, const short* __restrict__ re_l,
    const short* __restrict__ im_h, const short* __restrict__ im_l,
    const float2* __restrict__ lam, float2* __restrict__ carry)
{
  const int g = blockIdx.x * 256 + threadIdx.x;
  const int n = g & (NST - 1);
  const int c = (g >> 9) & (NC - 1);
  const int b = g >> 14;
  const float2 L = lam[n];
  const size_t cn = ((size_t)(n >> 5) << 9) + (size_t)(((n >> 3) & 3) << 7) + (n & 7);
  const size_t t0 = (size_t)(b * 256 + c * 8);         // starting m-tile
  float sr = 0.f, si = 0.f;
  for (int t16 = 0; t16 < 8; ++t16) {
    const size_t base = (t0 + t16) * 8192 + cn;
    #pragma unroll 4
    for (int r = 0; r < 16; ++r) {
      const size_t idx = base + (size_t)r * 8;
      const float br = s2f(re_h[idx]) + s2f(re_l[idx]);
      const float bi = s2f(im_h[idx]) + s2f(im_l[idx]);
      const float nr = fmaf(L.x, sr, fmaf(-L.y, si, br));
      const float ni = fmaf(L.x, si, fmaf( L.y, sr, bi));
      sr = nr; si = ni;
    }
  }
  carry[(size_t)(b * NC + c) * NST + n] = make_float2(sr, si);
}

// ---- scan phase 2 -------------------------------------------------------------------------
__global__ __launch_bounds__(256) void scan_carry(
    float2* __restrict__ carry, const float2* __restrict__ lamL)
{
  const int g = blockIdx.x * 256 + threadIdx.x;
  const int n = g & (NST - 1);
  const int b = g >> 9;
  const float2 P = lamL[n];
  float sr = 0.f, si = 0.f;
  for (int c = 0; c < NC; ++c) {
    const size_t idx = (size_t)(b * NC + c) * NST + n;
    const float2 v = carry[idx];
    carry[idx] = make_float2(sr, si);
    const float nr = fmaf(P.x, sr, fmaf(-P.y, si, v.x));
    const float ni = fmaf(P.x, si, fmaf( P.y, sr, v.y));
    sr = nr; si = ni;
  }
}

// ---- scan phase 3 (tiled layout, in place) ------------------------------------------------
__global__ __launch_bounds__(256) void scan_final(
    short* __restrict__ re_h, short* __restrict__ re_l,
    short* __restrict__ im_h, short* __restrict__ im_l,
    const float2* __restrict__ lam, const float2* __restrict__ carry)
{
  const int g = blockIdx.x * 256 + threadIdx.x;
  const int n = g & (NST - 1);
  const int c = (g >> 9) & (NC - 1);
  const int b = g >> 14;
  const float2 L = lam[n];
  const float2 ci = carry[(size_t)(b * NC + c) * NST + n];
  const size_t cn = ((size_t)(n >> 5) << 9) + (size_t)(((n >> 3) & 3) << 7) + (n & 7);
  const size_t t0 = (size_t)(b * 256 + c * 8);
  float sr = ci.x, si = ci.y;
  for (int t16 = 0; t16 < 8; ++t16) {
    const size_t base = (t0 + t16) * 8192 + cn;
    #pragma unroll 4
    for (int r = 0; r < 16; ++r) {
      const size_t idx = base + (size_t)r * 8;
      const float br = s2f(re_h[idx]) + s2f(re_l[idx]);
      const float bi = s2f(im_h[idx]) + s2f(im_l[idx]);
      const float nr = fmaf(L.x, sr, fmaf(-L.y, si, br));
      const float ni = fmaf(L.x, si, fmaf( L.y, sr, bi));
      sr = nr; si = ni;
      short hh, ll;
      split(sr, hh, ll); re_h[idx] = hh; re_l[idx] = ll;
      split(si, hh, ll); im_h[idx] = hh; im_l[idx] = ll;
    }
  }
}

// ---- kernel 5: y = st_re@Cre^T - st_im@Cim^T + x@D^T --------------------------------------
template<bool XAG>
__global__ __launch_bounds__(256, 2) void out_mfma(
    const short* __restrict__ re_h, const short* __restrict__ re_l,
    const short* __restrict__ im_h, const short* __restrict__ im_l,
    const float* __restrict__ x, const short* __restrict__ xh, const short* __restrict__ xl,
    const short* __restrict__ Crh, const short* __restrict__ Crl,
    const short* __restrict__ Cih, const short* __restrict__ Cil,  // Cim pre-negated
    const short* __restrict__ Dw,
    float* __restrict__ y)
{
  __shared__ short lds[16384];             // 32 KB
  f32x4 acc[4][4] = {};
  const int tid = threadIdx.x;
  int mb, nbk;
  map_mn(blockIdx.x, mb, nbk);
  const int m0 = mb * 128;
  const int o0 = nbk * 128;

  gemm_dir<16, 4>(re_h, re_l, NST, Crh, Crl, NST, m0, o0, tid, acc, lds);
  gemm_dir<16, 4>(im_h, im_l, NST, Cih, Cil, NST, m0, o0, tid, acc, lds);
  if constexpr (XAG)
    gemm_dir<32, 3>(xh, xl, DIN, Dw, nullptr, DIN, m0, o0, tid, acc, lds);
  else
    gemm_fb(x, Dw, DIN, DIN, DIN, m0, o0, tid, acc, lds);

  const int lane = tid & 63, w = tid >> 6, wm = w >> 1, wn = w & 1;
  const int lr = lane & 15, lq = lane >> 4;
  #pragma unroll
  for (int mi = 0; mi < 4; ++mi)
    #pragma unroll
    for (int j = 0; j < 4; ++j) {
      const size_t m = (size_t)m0 + wm * 64 + mi * 16 + lq * 4 + j;
      #pragma unroll
      for (int ni = 0; ni < 4; ++ni)
        y[m * DOUT + o0 + wn * 64 + ni * 16 + lr] = acc[mi][ni][j];
    }
}

// ---- host launch --------------------------------------------------------------------------
extern "C" void kernel_launch(void* const* d_in, const int* in_sizes, int n_in,
                              void* d_out, int out_size, void* d_ws, size_t ws_size,
                              hipStream_t stream)
{
  (void)in_sizes; (void)n_in; (void)out_size;
  const float* x     = (const float*)d_in[0];
  const float* nulog = (const float*)d_in[1];
  const float* thlog = (const float*)d_in[2];
  const float* glog  = (const float*)d_in[3];
  const float* Bre   = (const float*)d_in[4];
  const float* Bim   = (const float*)d_in[5];
  const float* Cre   = (const float*)d_in[6];
  const float* Cim   = (const float*)d_in[7];
  const float* Dm    = (const float*)d_in[8];
  float* y = (float*)d_out;

  // ws layout: 4 state planes (TILED) | carry | lam | lamL | gamma | weights | [x planes]
  const size_t PLANE  = (size_t)M_TOT * NST;
  const size_t XPLANE = (size_t)M_TOT * DIN;
  short*  re_h  = (short*)d_ws;
  short*  re_l  = re_h + PLANE;
  short*  im_h  = re_l + PLANE;
  short*  im_l  = im_h + PLANE;
  float2* carry = (float2*)(im_l + PLANE);
  float2* lam   = carry + (size_t)BSZ * NC * NST;
  float2* lamL  = lam + NST;
  float*  gamma = (float*)(lamL + NST);

  char* wp = (char*)(gamma + NST);
  wp = (char*)(((uintptr_t)wp + 255) & ~(uintptr_t)255);
  short* Brw = (short*)wp;                          // B single planes (row-major)
  short* Biw = Brw + (size_t)NST * DIN;
  short* Crh = Biw + (size_t)NST * DIN;             // C hi/lo planes (row-major)
  short* Crl = Crh + (size_t)DOUT * NST;
  short* Cih = Crl + (size_t)DOUT * NST;
  short* Cil = Cih + (size_t)DOUT * NST;
  short* Dw  = Cil + (size_t)DOUT * NST;            // D single plane (row-major)
  short* xh  = Dw  + (size_t)DOUT * DIN;            // x hi/lo planes (TILED L(1024))
  short* xl  = xh + XPLANE;
  const size_t needed_full = (size_t)((char*)(xl + XPLANE) - (char*)d_ws);
  const bool full = (ws_size >= needed_full);

  params_k<<<2, 256, 0, stream>>>(nulog, thlog, glog, lam, lamL, gamma);

  const int nB4 = (NST * DIN) / 4, nC4 = (DOUT * NST) / 4, nD4 = (DOUT * DIN) / 4;
  wround_k<<<(nB4 + 255) / 256, 256, 0, stream>>>(Bre, Brw, nB4);
  wround_k<<<(nB4 + 255) / 256, 256, 0, stream>>>(Bim, Biw, nB4);
  wsplit_k<<<(nC4 + 255) / 256, 256, 0, stream>>>(Cre, Crh, Crl, nC4,  1.0f);
  wsplit_k<<<(nC4 + 255) / 256, 256, 0, stream>>>(Cim, Cih, Cil, nC4, -1.0f);
  wround_k<<<(nD4 + 255) / 256, 256, 0, stream>>>(Dm, Dw, nD4);

  if (full) {
    wsplit_xt<<<(int)(XPLANE / 8 / 256), 256, 0, stream>>>(x, xh, xl);
    bu_mfma<true><<<2048, 256, 0, stream>>>(
        x, xh, xl, Brw, Biw, gamma, re_h, re_l, im_h, im_l);
  } else {
    bu_mfma<false><<<2048, 256, 0, stream>>>(
        x, xh, xl, Brw, Biw, gamma, re_h, re_l, im_h, im_l);
  }

  scan_partial<<<(BSZ * NC * NST) / 256, 256, 0, stream>>>(re_h, re_l, im_h, im_l, lam, carry);
  scan_carry<<<(BSZ * NST) / 256, 256, 0, stream>>>(carry, lamL);
  scan_final<<<(BSZ * NC * NST) / 256, 256, 0, stream>>>(re_h, re_l, im_h, im_l, lam, carry);

  if (full) {
    out_mfma<true><<<2048, 256, 0, stream>>>(
        re_h, re_l, im_h, im_l, x, xh, xl, Crh, Crl, Cih, Cil, Dw, y);
  } else {
    out_mfma<false><<<2048, 256, 0, stream>>>(
        re_h, re_l, im_h, im_l, x, xh, xl, Crh, Crl, Cih, Cil, Dw, y);
  }
}

// Round 9
// 599.360 us; speedup vs baseline: 1.1022x; 1.1022x over previous
//
#include <hip/hip_runtime.h>
#include <stdint.h>

// LRU forward: y = Re(scan(lam, gamma*(x@B^T)) @ C^T) + x @ D^T
// Round 9: r7 pipeline (DMA->LDS, quad-XOR swizzle, dbuf, counted vmcnt) with
// 8-wave 512-thread blocks and 64x32 wave tiles (acc[4][2]=32 AGPR) to double
// occupancy (2 -> 4 waves/SIMD). A/states planes row-major (r7 layout).

#define BSZ   8
#define TLEN  4096
#define DIN   1024
#define DOUT  1024
#define NST   512
#define M_TOT (BSZ * TLEN)   // 32768
#define NC    32
#define CL    128
#define PL    4096           // LDS plane: 128 rows x 32 shorts (8 KB)

typedef __attribute__((ext_vector_type(8))) short bf16x8;
typedef __attribute__((ext_vector_type(4))) float f32x4;

// ---- bf16 helpers -------------------------------------------------------------------------
__device__ __forceinline__ float s2f(short s) {
  unsigned v = ((unsigned)(unsigned short)s) << 16;
  return __builtin_bit_cast(float, v);
}
__device__ __forceinline__ short f2s_rne(float f) {
  unsigned u = __builtin_bit_cast(unsigned, f);
  unsigned r = (u + 0x7FFFu + ((u >> 16) & 1u)) >> 16;
  return (short)r;
}
// h = truncated-bf16(f) (residual exactly representable), l = RNE(f - h)
__device__ __forceinline__ void split(float f, short& h, short& l) {
  const unsigned u = __builtin_bit_cast(unsigned, f);
  h = (short)(u >> 16);
  const float fh = __builtin_bit_cast(float, u & 0xFFFF0000u);
  l = f2s_rne(f - fh);
}
__device__ __forceinline__ void split8(const float4 v0, const float4 v1,
                                       bf16x8& hv, bf16x8& lv) {
  const float f[8] = {v0.x, v0.y, v0.z, v0.w, v1.x, v1.y, v1.z, v1.w};
  #pragma unroll
  for (int j = 0; j < 8; ++j) { short hh, ll; split(f[j], hh, ll); hv[j] = hh; lv[j] = ll; }
}

// ---- async global->LDS, 16B per lane ------------------------------------------------------
__device__ __forceinline__ void gload16(const short* g, short* l) {
  __builtin_amdgcn_global_load_lds(
      (const __attribute__((address_space(1))) void*)g,
      (__attribute__((address_space(3))) void*)l, 16, 0, 0);
}

// Quad-XOR swizzle (verified r5-r8: 0 bank conflicts): data quad q of row r lives at
// slot quad q ^ ((r>>1)&3). DMA dest linear; SOURCE pre-permuted; ds_read applies XOR.

// ---- stage one K-tile: wave w stages chunk (rows w*16..+16) of each plane (NP loads) ------
// planes: 0=Ah(m0,lda) 1=Al 2=Bh(n0,ldb) 3=Bl
template<int NP>
__device__ __forceinline__ void stage8(
    const short* __restrict__ Aph, const short* __restrict__ Apl,
    const short* __restrict__ Bph, const short* __restrict__ Bpl,
    const int lda, const int ldb, const int m0, const int n0, const int k0,
    short* lbuf, const int w, const int lane)
{
  const int q  = (lane & 3) ^ ((lane >> 3) & 3);
  const int gr = lane >> 2;
  #pragma unroll
  for (int p = 0; p < NP; ++p) {
    const short* g = (p == 0) ? Aph : (p == 1) ? Apl : (p == 2) ? Bph : Bpl;
    const int r0 = (p < 2) ? m0 : n0;
    const int ld = (p < 2) ? lda : ldb;
    gload16(g + (size_t)(r0 + w * 16 + gr) * ld + k0 + q * 8, lbuf + p * PL + w * 512);
  }
}

// ---- pipelined GEMM: 8 waves, wave tile 64x32. NP=4 -> 3 MFMA, NP=3 -> 2 MFMA -------------
template<int NT, int NP>
__device__ __forceinline__ void gemm_pl8(
    const short* __restrict__ Aph, const short* __restrict__ Apl,
    const short* __restrict__ Bph, const short* __restrict__ Bpl,
    const int lda, const int ldb, const int m0, const int n0, const int tid,
    f32x4 (&acc)[4][2], short* lds)
{
  const int lane = tid & 63, w = tid >> 6, wm = w >> 2, wn = w & 3;
  const int BUF = NP * PL;
  stage8<NP>(Aph, Apl, Bph, Bpl, lda, ldb, m0, n0, 0,  lds,       w, lane);
  stage8<NP>(Aph, Apl, Bph, Bpl, lda, ldb, m0, n0, 32, lds + BUF, w, lane);

  for (int k = 0; k < NT; ++k) {
    if (k + 1 < NT) asm volatile("s_waitcnt vmcnt(%0)" :: "i"(NP) : "memory");
    else            asm volatile("s_waitcnt vmcnt(0)" ::: "memory");
    __builtin_amdgcn_s_barrier();          // batch-k DMA landed (all waves)

    short* cur = lds + (k & 1) * BUF;
    const int lr = lane & 15, kg = lane >> 4;
    const int qo = (kg ^ ((lr >> 1) & 3)) * 8;
    bf16x8 ah[4], al[4], bh[2], bl[2];
    #pragma unroll
    for (int mi = 0; mi < 4; ++mi) {
      const int ro = (wm * 64 + mi * 16 + lr) * 32 + qo;
      ah[mi] = *(const bf16x8*)&cur[ro];
      al[mi] = *(const bf16x8*)&cur[PL + ro];
    }
    #pragma unroll
    for (int ni = 0; ni < 2; ++ni) {
      const int co = (wn * 32 + ni * 16 + lr) * 32 + qo;
      bh[ni] = *(const bf16x8*)&cur[2 * PL + co];
      if constexpr (NP == 4) bl[ni] = *(const bf16x8*)&cur[3 * PL + co];
    }
    asm volatile("s_waitcnt lgkmcnt(0)" ::: "memory");
    __builtin_amdgcn_s_barrier();          // reads done -> safe to overwrite

    if (k + 2 < NT)                        // DMA flies under MFMAs below
      stage8<NP>(Aph, Apl, Bph, Bpl, lda, ldb, m0, n0, (k + 2) * 32, cur, w, lane);

    __builtin_amdgcn_s_setprio(1);
    #pragma unroll
    for (int ni = 0; ni < 2; ++ni)
      #pragma unroll
      for (int mi = 0; mi < 4; ++mi) {
        acc[mi][ni] = __builtin_amdgcn_mfma_f32_16x16x32_bf16(ah[mi], bh[ni], acc[mi][ni], 0, 0, 0);
        acc[mi][ni] = __builtin_amdgcn_mfma_f32_16x16x32_bf16(al[mi], bh[ni], acc[mi][ni], 0, 0, 0);
        if constexpr (NP == 4)
          acc[mi][ni] = __builtin_amdgcn_mfma_f32_16x16x32_bf16(ah[mi], bl[ni], acc[mi][ni], 0, 0, 0);
      }
    __builtin_amdgcn_s_setprio(0);
  }
}

// ---- fallback GEMM (x fp32 row-major, reg-split; B single plane), 512 threads -------------
__device__ __forceinline__ void gemm_fb8(
    const float* __restrict__ Af, const short* __restrict__ Bw,
    const int lda, const int ldb, const int K, const int m0, const int n0, const int tid,
    f32x4 (&acc)[4][2], short* lds)        // planes: Ah@0, Al@PL, B@2*PL (single buffer)
{
  const int lane = tid & 63, w = tid >> 6, wm = w >> 2, wn = w & 3;
  const int r = tid & 127, e = (tid >> 7) & 3;   // row, k-quad
  short *LAh = lds, *LAl = lds + PL, *LB = lds + 2 * PL;
  float4 pa[2];
  {
    const float* p = Af + (size_t)(m0 + r) * lda + e * 8;
    pa[0] = *(const float4*)(p);
    pa[1] = *(const float4*)(p + 4);
  }
  for (int k0 = 0; k0 < K; k0 += 32) {
    __syncthreads();
    {
      bf16x8 hv, lv;
      split8(pa[0], pa[1], hv, lv);
      const int f = (r >> 1) & 3;
      const int qq = (e ^ f) * 8;
      *(bf16x8*)&LAh[r * 32 + qq] = hv;
      *(bf16x8*)&LAl[r * 32 + qq] = lv;
    }
    {
      const int q = (lane & 3) ^ ((lane >> 3) & 3);
      const int gr = lane >> 2;
      gload16(Bw + (size_t)(n0 + w * 16 + gr) * ldb + k0 + q * 8, LB + w * 512);
    }
    __syncthreads();
    if (k0 + 32 < K) {
      const float* p = Af + (size_t)(m0 + r) * lda + (k0 + 32) + e * 8;
      pa[0] = *(const float4*)(p);
      pa[1] = *(const float4*)(p + 4);
    }
    const int lr = lane & 15, kg = lane >> 4;
    const int qo = (kg ^ ((lr >> 1) & 3)) * 8;
    bf16x8 ah[4], al[4], bh[2];
    #pragma unroll
    for (int mi = 0; mi < 4; ++mi) {
      const int ro = (wm * 64 + mi * 16 + lr) * 32 + qo;
      ah[mi] = *(const bf16x8*)&LAh[ro];
      al[mi] = *(const bf16x8*)&LAl[ro];
    }
    #pragma unroll
    for (int ni = 0; ni < 2; ++ni)
      bh[ni] = *(const bf16x8*)&LB[(wn * 32 + ni * 16 + lr) * 32 + qo];
    #pragma unroll
    for (int ni = 0; ni < 2; ++ni)
      #pragma unroll
      for (int mi = 0; mi < 4; ++mi) {
        acc[mi][ni] = __builtin_amdgcn_mfma_f32_16x16x32_bf16(ah[mi], bh[ni], acc[mi][ni], 0, 0, 0);
        acc[mi][ni] = __builtin_amdgcn_mfma_f32_16x16x32_bf16(al[mi], bh[ni], acc[mi][ni], 0, 0, 0);
      }
  }
  __syncthreads();
}

// ---- XCD-locality block mapping (verified r6: FETCH -70%) ---------------------------------
__device__ __forceinline__ void map_mn(const int bid, int& mb, int& nb) {
  const int xcd = bid & 7;
  const int j   = bid >> 3;
  mb = xcd * 32 + (j >> 3);
  nb = j & 7;
}

// ---- weight pre-split (hi/lo) and pre-round (single RNE), row-major -----------------------
__global__ __launch_bounds__(256) void wsplit_k(const float* __restrict__ src,
    short* __restrict__ h, short* __restrict__ l, const int n4, const float sgn)
{
  const int i = blockIdx.x * 256 + threadIdx.x;
  if (i >= n4) return;
  const float4 v = ((const float4*)src)[i];
  const float f[4] = {sgn * v.x, sgn * v.y, sgn * v.z, sgn * v.w};
  short4 hv, lv;
  split(f[0], hv.x, lv.x); split(f[1], hv.y, lv.y);
  split(f[2], hv.z, lv.z); split(f[3], hv.w, lv.w);
  ((short4*)h)[i] = hv;
  ((short4*)l)[i] = lv;
}
__global__ __launch_bounds__(256) void wround_k(const float* __restrict__ src,
    short* __restrict__ h, const int n4)
{
  const int i = blockIdx.x * 256 + threadIdx.x;
  if (i >= n4) return;
  const float4 v = ((const float4*)src)[i];
  short4 hv;
  hv.x = f2s_rne(v.x); hv.y = f2s_rne(v.y); hv.z = f2s_rne(v.z); hv.w = f2s_rne(v.w);
  ((short4*)h)[i] = hv;
}

// ---- kernel 1: Bu planes (row-major) = split(gamma * (x @ [Bre|Bim]^T)) -------------------
template<bool XAG>
__global__ __launch_bounds__(512, 4) void bu_mfma(
    const float* __restrict__ x, const short* __restrict__ xh, const short* __restrict__ xl,
    const short* __restrict__ Brw, const short* __restrict__ Biw,
    const float* __restrict__ gamma,
    short* __restrict__ re_h, short* __restrict__ re_l,
    short* __restrict__ im_h, short* __restrict__ im_l)
{
  __shared__ short lds[2 * 3 * PL];        // 48 KB
  f32x4 acc[4][2] = {};
  const int tid = threadIdx.x;
  int mb, nbk;
  map_mn(blockIdx.x, mb, nbk);
  const int m0  = mb * 128;
  const int n0s = nbk * 128;
  const bool re = (n0s < NST);
  const int nb0 = n0s & (NST - 1);
  const short* Bw = re ? Brw : Biw;

  if constexpr (XAG)
    gemm_pl8<32, 3>(xh, xl, Bw, nullptr, DIN, DIN, m0, nb0, tid, acc, lds);
  else
    gemm_fb8(x, Bw, DIN, DIN, DIN, m0, nb0, tid, acc, lds);

  short* Hp = re ? re_h : im_h;
  short* Lp = re ? re_l : im_l;
  const int lane = tid & 63, w = tid >> 6, wm = w >> 2, wn = w & 3;
  const int lr = lane & 15, lq = lane >> 4;
  #pragma unroll
  for (int ni = 0; ni < 2; ++ni) {
    const int nb = nb0 + wn * 32 + ni * 16 + lr;
    const float g = gamma[nb];
    #pragma unroll
    for (int mi = 0; mi < 4; ++mi)
      #pragma unroll
      for (int j = 0; j < 4; ++j) {
        const size_t m = (size_t)m0 + wm * 64 + mi * 16 + lq * 4 + j;
        short hh, ll;
        split(acc[mi][ni][j] * g, hh, ll);
        Hp[m * NST + nb] = hh;
        Lp[m * NST + nb] = ll;
      }
  }
}

// ---- scan params --------------------------------------------------------------------------
__global__ void params_k(const float* __restrict__ nulog, const float* __restrict__ thlog,
                         const float* __restrict__ glog,
                         float2* __restrict__ lam, float2* __restrict__ lamL,
                         float* __restrict__ gamma)
{
  const int n = blockIdx.x * 256 + threadIdx.x;
  if (n >= NST) return;
  const float nu = expf(nulog[n]);
  const float th = expf(thlog[n]);
  const float mod = expf(-nu);
  float s, c;
  sincosf(th, &s, &c);
  lam[n] = make_float2(mod * c, mod * s);
  const float modL = expf(-(float)CL * nu);
  float sL, cL;
  sincosf((float)CL * th, &sL, &cL);
  lamL[n] = make_float2(modL * cL, modL * sL);
  gamma[n] = expf(glog[n]);
}

// ---- scan phase 1 -------------------------------------------------------------------------
__global__ __launch_bounds__(256) void scan_partial(
    const short* __restrict__ re_h, const short* __restrict__ re_l,
    const short* __restrict__ im_h, const short* __restrict__ im_l,
    const float2* __restrict__ lam, float2* __restrict__ carry)
{
  const int g = blockIdx.x * 256 + threadIdx.x;
  const int n = g & (NST - 1);
  const int c = (g >> 9) & (NC - 1);
  const int b = g >> 14;
  const float2 L = lam[n];
  size_t idx = ((size_t)b * TLEN + (size_t)c * CL) * NST + n;
  float sr = 0.f, si = 0.f;
  #pragma unroll 4
  for (int t = 0; t < CL; ++t, idx += NST) {
    const float br = s2f(re_h[idx]) + s2f(re_l[idx]);
    const float bi = s2f(im_h[idx]) + s2f(im_l[idx]);
    const float nr = fmaf(L.x, sr, fmaf(-L.y, si, br));
    const float ni = fmaf(L.x, si, fmaf( L.y, sr, bi));
    sr = nr; si = ni;
  }
  carry[(size_t)(b * NC + c) * NST + n] = make_float2(sr, si);
}

// ---- scan phase 2 -------------------------------------------------------------------------
__global__ __launch_bounds__(256) void scan_carry(
    float2* __restrict__ carry, const float2* __restrict__ lamL)
{
  const int g = blockIdx.x * 256 + threadIdx.x;
  const int n = g & (NST - 1);
  const int b = g >> 9;
  const float2 P = lamL[n];
  float sr = 0.f, si = 0.f;
  for (int c = 0; c < NC; ++c) {
    const size_t idx = (size_t)(b * NC + c) * NST + n;
    const float2 v = carry[idx];
    carry[idx] = make_float2(sr, si);
    const float nr = fmaf(P.x, sr, fmaf(-P.y, si, v.x));
    const float ni = fmaf(P.x, si, fmaf( P.y, sr, v.y));
    sr = nr; si = ni;
  }
}

// ---- scan phase 3 -------------------------------------------------------------------------
__global__ __launch_bounds__(256) void scan_final(
    short* __restrict__ re_h, short* __restrict__ re_l,
    short* __restrict__ im_h, short* __restrict__ im_l,
    const float2* __restrict__ lam, const float2* __restrict__ carry)
{
  const int g = blockIdx.x * 256 + threadIdx.x;
  const int n = g & (NST - 1);
  const int c = (g >> 9) & (NC - 1);
  const int b = g >> 14;
  const float2 L = lam[n];
  const float2 ci = carry[(size_t)(b * NC + c) * NST + n];
  size_t idx = ((size_t)b * TLEN + (size_t)c * CL) * NST + n;
  float sr = ci.x, si = ci.y;
  #pragma unroll 4
  for (int t = 0; t < CL; ++t, idx += NST) {
    const float br = s2f(re_h[idx]) + s2f(re_l[idx]);
    const float bi = s2f(im_h[idx]) + s2f(im_l[idx]);
    const float nr = fmaf(L.x, sr, fmaf(-L.y, si, br));
    const float ni = fmaf(L.x, si, fmaf( L.y, sr, bi));
    sr = nr; si = ni;
    short hh, ll;
    split(sr, hh, ll); re_h[idx] = hh; re_l[idx] = ll;
    split(si, hh, ll); im_h[idx] = hh; im_l[idx] = ll;
  }
}

// ---- kernel 5: y = st_re@Cre^T - st_im@Cim^T + x@D^T --------------------------------------
// C phases: NP=4 (C hi/lo, 3 MFMA); D phase: NP=3 (D single, 2 MFMA).
template<bool XAG>
__global__ __launch_bounds__(512, 4) void out_mfma(
    const short* __restrict__ re_h, const short* __restrict__ re_l,
    const short* __restrict__ im_h, const short* __restrict__ im_l,
    const float* __restrict__ x, const short* __restrict__ xh, const short* __restrict__ xl,
    const short* __restrict__ Crh, const short* __restrict__ Crl,
    const short* __restrict__ Cih, const short* __restrict__ Cil,  // Cim pre-negated
    const short* __restrict__ Dw,
    float* __restrict__ y)
{
  __shared__ short lds[2 * 4 * PL];        // 64 KB
  f32x4 acc[4][2] = {};
  const int tid = threadIdx.x;
  int mb, nbk;
  map_mn(blockIdx.x, mb, nbk);
  const int m0 = mb * 128;
  const int o0 = nbk * 128;

  gemm_pl8<16, 4>(re_h, re_l, Crh, Crl, NST, NST, m0, o0, tid, acc, lds);
  gemm_pl8<16, 4>(im_h, im_l, Cih, Cil, NST, NST, m0, o0, tid, acc, lds);
  if constexpr (XAG)
    gemm_pl8<32, 3>(xh, xl, Dw, nullptr, DIN, DIN, m0, o0, tid, acc, lds);
  else
    gemm_fb8(x, Dw, DIN, DIN, DIN, m0, o0, tid, acc, lds);

  const int lane = tid & 63, w = tid >> 6, wm = w >> 2, wn = w & 3;
  const int lr = lane & 15, lq = lane >> 4;
  #pragma unroll
  for (int mi = 0; mi < 4; ++mi)
    #pragma unroll
    for (int j = 0; j < 4; ++j) {
      const size_t m = (size_t)m0 + wm * 64 + mi * 16 + lq * 4 + j;
      #pragma unroll
      for (int ni = 0; ni < 2; ++ni)
        y[m * DOUT + o0 + wn * 32 + ni * 16 + lr] = acc[mi][ni][j];
    }
}

// ---- host launch --------------------------------------------------------------------------
extern "C" void kernel_launch(void* const* d_in, const int* in_sizes, int n_in,
                              void* d_out, int out_size, void* d_ws, size_t ws_size,
                              hipStream_t stream)
{
  (void)in_sizes; (void)n_in; (void)out_size;
  const float* x     = (const float*)d_in[0];
  const float* nulog = (const float*)d_in[1];
  const float* thlog = (const float*)d_in[2];
  const float* glog  = (const float*)d_in[3];
  const float* Bre   = (const float*)d_in[4];
  const float* Bim   = (const float*)d_in[5];
  const float* Cre   = (const float*)d_in[6];
  const float* Cim   = (const float*)d_in[7];
  const float* Dm    = (const float*)d_in[8];
  float* y = (float*)d_out;

  // ws layout: 4 state planes | carry | lam | lamL | gamma | weight planes | [x planes]
  const size_t PLANE  = (size_t)M_TOT * NST;
  const size_t XPLANE = (size_t)M_TOT * DIN;
  short*  re_h  = (short*)d_ws;
  short*  re_l  = re_h + PLANE;
  short*  im_h  = re_l + PLANE;
  short*  im_l  = im_h + PLANE;
  float2* carry = (float2*)(im_l + PLANE);
  float2* lam   = carry + (size_t)BSZ * NC * NST;
  float2* lamL  = lam + NST;
  float*  gamma = (float*)(lamL + NST);

  char* wp = (char*)(gamma + NST);
  wp = (char*)(((uintptr_t)wp + 255) & ~(uintptr_t)255);
  short* Brw = (short*)wp;                          // B single planes
  short* Biw = Brw + (size_t)NST * DIN;
  short* Crh = Biw + (size_t)NST * DIN;             // C hi/lo planes
  short* Crl = Crh + (size_t)DOUT * NST;
  short* Cih = Crl + (size_t)DOUT * NST;
  short* Cil = Cih + (size_t)DOUT * NST;
  short* Dw  = Cil + (size_t)DOUT * NST;            // D single plane
  short* xh  = Dw  + (size_t)DOUT * DIN;            // x hi/lo planes (row-major)
  short* xl  = xh + XPLANE;
  const size_t needed_full = (size_t)((char*)(xl + XPLANE) - (char*)d_ws);
  const bool full = (ws_size >= needed_full);

  params_k<<<2, 256, 0, stream>>>(nulog, thlog, glog, lam, lamL, gamma);

  const int nB4 = (NST * DIN) / 4, nC4 = (DOUT * NST) / 4, nD4 = (DOUT * DIN) / 4;
  wround_k<<<(nB4 + 255) / 256, 256, 0, stream>>>(Bre, Brw, nB4);
  wround_k<<<(nB4 + 255) / 256, 256, 0, stream>>>(Bim, Biw, nB4);
  wsplit_k<<<(nC4 + 255) / 256, 256, 0, stream>>>(Cre, Crh, Crl, nC4,  1.0f);
  wsplit_k<<<(nC4 + 255) / 256, 256, 0, stream>>>(Cim, Cih, Cil, nC4, -1.0f);
  wround_k<<<(nD4 + 255) / 256, 256, 0, stream>>>(Dm, Dw, nD4);

  if (full) {
    const int nX4 = (int)(XPLANE / 4);
    wsplit_k<<<(nX4 + 255) / 256, 256, 0, stream>>>(x, xh, xl, nX4, 1.0f);
    bu_mfma<true><<<2048, 512, 0, stream>>>(
        x, xh, xl, Brw, Biw, gamma, re_h, re_l, im_h, im_l);
  } else {
    bu_mfma<false><<<2048, 512, 0, stream>>>(
        x, xh, xl, Brw, Biw, gamma, re_h, re_l, im_h, im_l);
  }

  scan_partial<<<(BSZ * NC * NST) / 256, 256, 0, stream>>>(re_h, re_l, im_h, im_l, lam, carry);
  scan_carry<<<(BSZ * NST) / 256, 256, 0, stream>>>(carry, lamL);
  scan_final<<<(BSZ * NC * NST) / 256, 256, 0, stream>>>(re_h, re_l, im_h, im_l, lam, carry);

  if (full) {
    out_mfma<true><<<2048, 512, 0, stream>>>(
        re_h, re_l, im_h, im_l, x, xh, xl, Crh, Crl, Cih, Cil, Dw, y);
  } else {
    out_mfma<false><<<2048, 512, 0, stream>>>(
        re_h, re_l, im_h, im_l, x, xh, xl, Crh, Crl, Cih, Cil, Dw, y);
  }
}

// Round 10
// 584.503 us; speedup vs baseline: 1.1302x; 1.0254x over previous
//
#include <hip/hip_runtime.h>
#include <stdint.h>

// LRU forward: y = Re(scan(lam, gamma*(x@B^T)) @ C^T) + x @ D^T
// Round 10: 8-wave 512-thread blocks, 128x256 tile, 64x64 wave tiles (acc[4][4]),
// ALL weights single RNE bf16 plane (2 MFMA/product: Ah*W + Al*W), A hi/lo kept.
// LDS 32KB/buffer dbuf (Ah|Al|W), DMA+quad-XOR swizzle, counted vmcnt(4), setprio.

#define BSZ   8
#define TLEN  4096
#define DIN   1024
#define DOUT  1024
#define NST   512
#define M_TOT (BSZ * TLEN)   // 32768
#define NC    32
#define CL    128
#define PLA   4096           // A plane: 128 rows x 32 shorts (8 KB)
#define PLB   8192           // B plane: 256 rows x 32 shorts (16 KB)
#define BUFS  16384          // shorts per buffer (32 KB): Ah@0, Al@4096, W@8192

typedef __attribute__((ext_vector_type(8))) short bf16x8;
typedef __attribute__((ext_vector_type(4))) float f32x4;

// ---- bf16 helpers -------------------------------------------------------------------------
__device__ __forceinline__ float s2f(short s) {
  unsigned v = ((unsigned)(unsigned short)s) << 16;
  return __builtin_bit_cast(float, v);
}
__device__ __forceinline__ short f2s_rne(float f) {
  unsigned u = __builtin_bit_cast(unsigned, f);
  unsigned r = (u + 0x7FFFu + ((u >> 16) & 1u)) >> 16;
  return (short)r;
}
// h = truncated-bf16(f) (residual exactly representable), l = RNE(f - h)
__device__ __forceinline__ void split(float f, short& h, short& l) {
  const unsigned u = __builtin_bit_cast(unsigned, f);
  h = (short)(u >> 16);
  const float fh = __builtin_bit_cast(float, u & 0xFFFF0000u);
  l = f2s_rne(f - fh);
}
__device__ __forceinline__ void split8(const float4 v0, const float4 v1,
                                       bf16x8& hv, bf16x8& lv) {
  const float f[8] = {v0.x, v0.y, v0.z, v0.w, v1.x, v1.y, v1.z, v1.w};
  #pragma unroll
  for (int j = 0; j < 8; ++j) { short hh, ll; split(f[j], hh, ll); hv[j] = hh; lv[j] = ll; }
}

// ---- async global->LDS, 16B per lane ------------------------------------------------------
__device__ __forceinline__ void gload16(const short* g, short* l) {
  __builtin_amdgcn_global_load_lds(
      (const __attribute__((address_space(1))) void*)g,
      (__attribute__((address_space(3))) void*)l, 16, 0, 0);
}

// Quad-XOR swizzle (verified r5-r9: 0 conflicts): data quad q of row r -> slot q^((r>>1)&3);
// DMA dest linear, SOURCE pre-permuted, ds_read applies the XOR.

// ---- stage one K-tile (32 chunks of 16 rows x 32 shorts); wave w -> chunks 4w..4w+3 -------
// chunks 0-7: Ah rows, 8-15: Al rows, 16-31: W rows.
__device__ __forceinline__ void stage_cx(
    const short* __restrict__ Ahg, const short* __restrict__ Alg,
    const short* __restrict__ Wg, const int lda, const int ldb,
    const int m0, const int n0, const int k0,
    short* lbuf, const int w, const int lane)
{
  const int q  = (lane & 3) ^ ((lane >> 3) & 3);
  const int gr = lane >> 2;
  #pragma unroll
  for (int j = 0; j < 4; ++j) {
    const int ch = w * 4 + j;
    const short* g;
    int r0, ld;
    if (ch < 8)       { g = Ahg; r0 = m0 + ch * 16;        ld = lda; }
    else if (ch < 16) { g = Alg; r0 = m0 + (ch - 8) * 16;  ld = lda; }
    else              { g = Wg;  r0 = n0 + (ch - 16) * 16; ld = ldb; }
    gload16(g + (size_t)(r0 + gr) * ld + k0 + q * 8, lbuf + ch * 512);
  }
}

// ---- pipelined GEMM: 8 waves, wave tile 64x64, 2 MFMA/product (Ah*W + Al*W) ---------------
template<int NT>
__device__ __forceinline__ void gemm_pl(
    const short* __restrict__ Aph, const short* __restrict__ Apl,
    const short* __restrict__ Wp, const int lda, const int ldb,
    const int m0, const int n0, const int tid,
    f32x4 (&acc)[4][4], short* lds)
{
  const int lane = tid & 63, w = tid >> 6, wm = w >> 2, wn = w & 3;
  stage_cx(Aph, Apl, Wp, lda, ldb, m0, n0, 0,  lds,        w, lane);
  stage_cx(Aph, Apl, Wp, lda, ldb, m0, n0, 32, lds + BUFS, w, lane);

  for (int k = 0; k < NT; ++k) {
    if (k + 1 < NT) asm volatile("s_waitcnt vmcnt(4)" ::: "memory");
    else            asm volatile("s_waitcnt vmcnt(0)" ::: "memory");
    __builtin_amdgcn_s_barrier();          // batch-k DMA landed (all waves)

    short* cur = lds + (k & 1) * BUFS;
    const int lr = lane & 15, kg = lane >> 4;
    const int qo = (kg ^ ((lr >> 1) & 3)) * 8;
    bf16x8 ah[4], al[4], bw[4];
    #pragma unroll
    for (int mi = 0; mi < 4; ++mi) {
      const int ro = (wm * 64 + mi * 16 + lr) * 32 + qo;
      ah[mi] = *(const bf16x8*)&cur[ro];
      al[mi] = *(const bf16x8*)&cur[PLA + ro];
    }
    #pragma unroll
    for (int ni = 0; ni < 4; ++ni) {
      const int co = (wn * 64 + ni * 16 + lr) * 32 + qo;
      bw[ni] = *(const bf16x8*)&cur[2 * PLA + co];
    }
    asm volatile("s_waitcnt lgkmcnt(0)" ::: "memory");
    __builtin_amdgcn_s_barrier();          // reads done -> safe to overwrite

    if (k + 2 < NT)                        // DMA flies under MFMAs below
      stage_cx(Aph, Apl, Wp, lda, ldb, m0, n0, (k + 2) * 32, cur, w, lane);

    __builtin_amdgcn_s_setprio(1);
    #pragma unroll
    for (int ni = 0; ni < 4; ++ni)
      #pragma unroll
      for (int mi = 0; mi < 4; ++mi) {
        acc[mi][ni] = __builtin_amdgcn_mfma_f32_16x16x32_bf16(ah[mi], bw[ni], acc[mi][ni], 0, 0, 0);
        acc[mi][ni] = __builtin_amdgcn_mfma_f32_16x16x32_bf16(al[mi], bw[ni], acc[mi][ni], 0, 0, 0);
      }
    __builtin_amdgcn_s_setprio(0);
  }
}

// ---- fallback GEMM (x fp32 row-major, reg-split; W single plane), 512 threads -------------
__device__ __forceinline__ void gemm_fb(
    const float* __restrict__ Af, const short* __restrict__ Wp,
    const int lda, const int ldb, const int K, const int m0, const int n0, const int tid,
    f32x4 (&acc)[4][4], short* lds)        // single buffer: Ah@0, Al@PLA, W@2*PLA
{
  const int lane = tid & 63, w = tid >> 6, wm = w >> 2, wn = w & 3;
  const int r = tid & 127, e = (tid >> 7) & 3;   // row, k-quad
  short *LAh = lds, *LAl = lds + PLA, *LB = lds + 2 * PLA;
  float4 pa[2];
  {
    const float* p = Af + (size_t)(m0 + r) * lda + e * 8;
    pa[0] = *(const float4*)(p);
    pa[1] = *(const float4*)(p + 4);
  }
  for (int k0 = 0; k0 < K; k0 += 32) {
    __syncthreads();
    {
      bf16x8 hv, lv;
      split8(pa[0], pa[1], hv, lv);
      const int f = (r >> 1) & 3;
      const int qq = (e ^ f) * 8;
      *(bf16x8*)&LAh[r * 32 + qq] = hv;
      *(bf16x8*)&LAl[r * 32 + qq] = lv;
    }
    {
      const int q = (lane & 3) ^ ((lane >> 3) & 3);
      const int gr = lane >> 2;
      #pragma unroll
      for (int i = 0; i < 2; ++i)
        gload16(Wp + (size_t)(n0 + (2 * w + i) * 16 + gr) * ldb + k0 + q * 8,
                LB + (2 * w + i) * 512);
    }
    __syncthreads();
    if (k0 + 32 < K) {
      const float* p = Af + (size_t)(m0 + r) * lda + (k0 + 32) + e * 8;
      pa[0] = *(const float4*)(p);
      pa[1] = *(const float4*)(p + 4);
    }
    const int lr = lane & 15, kg = lane >> 4;
    const int qo = (kg ^ ((lr >> 1) & 3)) * 8;
    bf16x8 ah[4], al[4], bw[4];
    #pragma unroll
    for (int mi = 0; mi < 4; ++mi) {
      const int ro = (wm * 64 + mi * 16 + lr) * 32 + qo;
      ah[mi] = *(const bf16x8*)&LAh[ro];
      al[mi] = *(const bf16x8*)&LAl[ro];
    }
    #pragma unroll
    for (int ni = 0; ni < 4; ++ni)
      bw[ni] = *(const bf16x8*)&LB[(wn * 64 + ni * 16 + lr) * 32 + qo];
    #pragma unroll
    for (int ni = 0; ni < 4; ++ni)
      #pragma unroll
      for (int mi = 0; mi < 4; ++mi) {
        acc[mi][ni] = __builtin_amdgcn_mfma_f32_16x16x32_bf16(ah[mi], bw[ni], acc[mi][ni], 0, 0, 0);
        acc[mi][ni] = __builtin_amdgcn_mfma_f32_16x16x32_bf16(al[mi], bw[ni], acc[mi][ni], 0, 0, 0);
      }
  }
  __syncthreads();
}

// ---- XCD-locality block mapping: grid 1024 = 256 m-blocks x 4 n-blocks --------------------
__device__ __forceinline__ void map_mn4(const int bid, int& mb, int& nb) {
  const int xcd = bid & 7;
  const int j   = bid >> 3;       // 0..127
  mb = xcd * 32 + (j >> 2);       // 0..255
  nb = j & 3;                     // 0..3
}

// ---- weight pre-round (single RNE, signed) and x pre-split --------------------------------
__global__ __launch_bounds__(256) void wround_k(const float* __restrict__ src,
    short* __restrict__ h, const int n4, const float sgn)
{
  const int i = blockIdx.x * 256 + threadIdx.x;
  if (i >= n4) return;
  const float4 v = ((const float4*)src)[i];
  short4 hv;
  hv.x = f2s_rne(sgn * v.x); hv.y = f2s_rne(sgn * v.y);
  hv.z = f2s_rne(sgn * v.z); hv.w = f2s_rne(sgn * v.w);
  ((short4*)h)[i] = hv;
}
__global__ __launch_bounds__(256) void wsplit_k(const float* __restrict__ src,
    short* __restrict__ h, short* __restrict__ l, const int n4)
{
  const int i = blockIdx.x * 256 + threadIdx.x;
  if (i >= n4) return;
  const float4 v = ((const float4*)src)[i];
  short4 hv, lv;
  split(v.x, hv.x, lv.x); split(v.y, hv.y, lv.y);
  split(v.z, hv.z, lv.z); split(v.w, hv.w, lv.w);
  ((short4*)h)[i] = hv;
  ((short4*)l)[i] = lv;
}

// ---- kernel 1: Bu planes (row-major) = split(gamma * (x @ [Bre|Bim]^T)) -------------------
template<bool XAG>
__global__ __launch_bounds__(512, 4) void bu_mfma(
    const float* __restrict__ x, const short* __restrict__ xh, const short* __restrict__ xl,
    const short* __restrict__ Brw, const short* __restrict__ Biw,
    const float* __restrict__ gamma,
    short* __restrict__ re_h, short* __restrict__ re_l,
    short* __restrict__ im_h, short* __restrict__ im_l)
{
  __shared__ short lds[2 * BUFS];          // 64 KB
  f32x4 acc[4][4] = {};
  const int tid = threadIdx.x;
  int mb, nbk;
  map_mn4(blockIdx.x, mb, nbk);
  const int m0  = mb * 128;
  const int n0s = nbk * 256;               // 0,256 -> re; 512,768 -> im
  const bool re = (n0s < NST);
  const int nb0 = n0s & (NST - 1);
  const short* Bw = re ? Brw : Biw;

  if constexpr (XAG)
    gemm_pl<32>(xh, xl, Bw, DIN, DIN, m0, nb0, tid, acc, lds);
  else
    gemm_fb(x, Bw, DIN, DIN, DIN, m0, nb0, tid, acc, lds);

  short* Hp = re ? re_h : im_h;
  short* Lp = re ? re_l : im_l;
  const int lane = tid & 63, w = tid >> 6, wm = w >> 2, wn = w & 3;
  const int lr = lane & 15, lq = lane >> 4;
  #pragma unroll
  for (int ni = 0; ni < 4; ++ni) {
    const int nb = nb0 + wn * 64 + ni * 16 + lr;
    const float g = gamma[nb];
    #pragma unroll
    for (int mi = 0; mi < 4; ++mi)
      #pragma unroll
      for (int j = 0; j < 4; ++j) {
        const size_t m = (size_t)m0 + wm * 64 + mi * 16 + lq * 4 + j;
        short hh, ll;
        split(acc[mi][ni][j] * g, hh, ll);
        Hp[m * NST + nb] = hh;
        Lp[m * NST + nb] = ll;
      }
  }
}

// ---- scan params --------------------------------------------------------------------------
__global__ void params_k(const float* __restrict__ nulog, const float* __restrict__ thlog,
                         const float* __restrict__ glog,
                         float2* __restrict__ lam, float2* __restrict__ lamL,
                         float* __restrict__ gamma)
{
  const int n = blockIdx.x * 256 + threadIdx.x;
  if (n >= NST) return;
  const float nu = expf(nulog[n]);
  const float th = expf(thlog[n]);
  const float mod = expf(-nu);
  float s, c;
  sincosf(th, &s, &c);
  lam[n] = make_float2(mod * c, mod * s);
  const float modL = expf(-(float)CL * nu);
  float sL, cL;
  sincosf((float)CL * th, &sL, &cL);
  lamL[n] = make_float2(modL * cL, modL * sL);
  gamma[n] = expf(glog[n]);
}

// ---- scan phase 1 -------------------------------------------------------------------------
__global__ __launch_bounds__(256) void scan_partial(
    const short* __restrict__ re_h, const short* __restrict__ re_l,
    const short* __restrict__ im_h, const short* __restrict__ im_l,
    const float2* __restrict__ lam, float2* __restrict__ carry)
{
  const int g = blockIdx.x * 256 + threadIdx.x;
  const int n = g & (NST - 1);
  const int c = (g >> 9) & (NC - 1);
  const int b = g >> 14;
  const float2 L = lam[n];
  size_t idx = ((size_t)b * TLEN + (size_t)c * CL) * NST + n;
  float sr = 0.f, si = 0.f;
  #pragma unroll 4
  for (int t = 0; t < CL; ++t, idx += NST) {
    const float br = s2f(re_h[idx]) + s2f(re_l[idx]);
    const float bi = s2f(im_h[idx]) + s2f(im_l[idx]);
    const float nr = fmaf(L.x, sr, fmaf(-L.y, si, br));
    const float ni = fmaf(L.x, si, fmaf( L.y, sr, bi));
    sr = nr; si = ni;
  }
  carry[(size_t)(b * NC + c) * NST + n] = make_float2(sr, si);
}

// ---- scan phase 2 -------------------------------------------------------------------------
__global__ __launch_bounds__(256) void scan_carry(
    float2* __restrict__ carry, const float2* __restrict__ lamL)
{
  const int g = blockIdx.x * 256 + threadIdx.x;
  const int n = g & (NST - 1);
  const int b = g >> 9;
  const float2 P = lamL[n];
  float sr = 0.f, si = 0.f;
  for (int c = 0; c < NC; ++c) {
    const size_t idx = (size_t)(b * NC + c) * NST + n;
    const float2 v = carry[idx];
    carry[idx] = make_float2(sr, si);
    const float nr = fmaf(P.x, sr, fmaf(-P.y, si, v.x));
    const float ni = fmaf(P.x, si, fmaf( P.y, sr, v.y));
    sr = nr; si = ni;
  }
}

// ---- scan phase 3 -------------------------------------------------------------------------
__global__ __launch_bounds__(256) void scan_final(
    short* __restrict__ re_h, short* __restrict__ re_l,
    short* __restrict__ im_h, short* __restrict__ im_l,
    const float2* __restrict__ lam, const float2* __restrict__ carry)
{
  const int g = blockIdx.x * 256 + threadIdx.x;
  const int n = g & (NST - 1);
  const int c = (g >> 9) & (NC - 1);
  const int b = g >> 14;
  const float2 L = lam[n];
  const float2 ci = carry[(size_t)(b * NC + c) * NST + n];
  size_t idx = ((size_t)b * TLEN + (size_t)c * CL) * NST + n;
  float sr = ci.x, si = ci.y;
  #pragma unroll 4
  for (int t = 0; t < CL; ++t, idx += NST) {
    const float br = s2f(re_h[idx]) + s2f(re_l[idx]);
    const float bi = s2f(im_h[idx]) + s2f(im_l[idx]);
    const float nr = fmaf(L.x, sr, fmaf(-L.y, si, br));
    const float ni = fmaf(L.x, si, fmaf( L.y, sr, bi));
    sr = nr; si = ni;
    short hh, ll;
    split(sr, hh, ll); re_h[idx] = hh; re_l[idx] = ll;
    split(si, hh, ll); im_h[idx] = hh; im_l[idx] = ll;
  }
}

// ---- kernel 5: y = st_re@Cre^T - st_im@Cim^T + x@D^T --------------------------------------
template<bool XAG>
__global__ __launch_bounds__(512, 4) void out_mfma(
    const short* __restrict__ re_h, const short* __restrict__ re_l,
    const short* __restrict__ im_h, const short* __restrict__ im_l,
    const float* __restrict__ x, const short* __restrict__ xh, const short* __restrict__ xl,
    const short* __restrict__ Crw, const short* __restrict__ Ciw,  // Cim pre-negated
    const short* __restrict__ Dw,
    float* __restrict__ y)
{
  __shared__ short lds[2 * BUFS];          // 64 KB
  f32x4 acc[4][4] = {};
  const int tid = threadIdx.x;
  int mb, nbk;
  map_mn4(blockIdx.x, mb, nbk);
  const int m0 = mb * 128;
  const int o0 = nbk * 256;

  gemm_pl<16>(re_h, re_l, Crw, NST, NST, m0, o0, tid, acc, lds);
  gemm_pl<16>(im_h, im_l, Ciw, NST, NST, m0, o0, tid, acc, lds);
  if constexpr (XAG)
    gemm_pl<32>(xh, xl, Dw, DIN, DIN, m0, o0, tid, acc, lds);
  else
    gemm_fb(x, Dw, DIN, DIN, DIN, m0, o0, tid, acc, lds);

  const int lane = tid & 63, w = tid >> 6, wm = w >> 2, wn = w & 3;
  const int lr = lane & 15, lq = lane >> 4;
  #pragma unroll
  for (int mi = 0; mi < 4; ++mi)
    #pragma unroll
    for (int j = 0; j < 4; ++j) {
      const size_t m = (size_t)m0 + wm * 64 + mi * 16 + lq * 4 + j;
      #pragma unroll
      for (int ni = 0; ni < 4; ++ni)
        y[m * DOUT + o0 + wn * 64 + ni * 16 + lr] = acc[mi][ni][j];
    }
}

// ---- host launch --------------------------------------------------------------------------
extern "C" void kernel_launch(void* const* d_in, const int* in_sizes, int n_in,
                              void* d_out, int out_size, void* d_ws, size_t ws_size,
                              hipStream_t stream)
{
  (void)in_sizes; (void)n_in; (void)out_size;
  const float* x     = (const float*)d_in[0];
  const float* nulog = (const float*)d_in[1];
  const float* thlog = (const float*)d_in[2];
  const float* glog  = (const float*)d_in[3];
  const float* Bre   = (const float*)d_in[4];
  const float* Bim   = (const float*)d_in[5];
  const float* Cre   = (const float*)d_in[6];
  const float* Cim   = (const float*)d_in[7];
  const float* Dm    = (const float*)d_in[8];
  float* y = (float*)d_out;

  // ws layout: 4 state planes | carry | lam | lamL | gamma | weight planes | [x planes]
  const size_t PLANE  = (size_t)M_TOT * NST;
  const size_t XPLANE = (size_t)M_TOT * DIN;
  short*  re_h  = (short*)d_ws;
  short*  re_l  = re_h + PLANE;
  short*  im_h  = re_l + PLANE;
  short*  im_l  = im_h + PLANE;
  float2* carry = (float2*)(im_l + PLANE);
  float2* lam   = carry + (size_t)BSZ * NC * NST;
  float2* lamL  = lam + NST;
  float*  gamma = (float*)(lamL + NST);

  char* wp = (char*)(gamma + NST);
  wp = (char*)(((uintptr_t)wp + 255) & ~(uintptr_t)255);
  short* Brw = (short*)wp;                          // single RNE planes
  short* Biw = Brw + (size_t)NST * DIN;
  short* Crw = Biw + (size_t)NST * DIN;
  short* Ciw = Crw + (size_t)DOUT * NST;            // pre-negated
  short* Dw  = Ciw + (size_t)DOUT * NST;
  short* xh  = Dw  + (size_t)DOUT * DIN;            // x hi/lo (row-major)
  short* xl  = xh + XPLANE;
  const size_t needed_full = (size_t)((char*)(xl + XPLANE) - (char*)d_ws);
  const bool full = (ws_size >= needed_full);

  params_k<<<2, 256, 0, stream>>>(nulog, thlog, glog, lam, lamL, gamma);

  const int nB4 = (NST * DIN) / 4, nC4 = (DOUT * NST) / 4, nD4 = (DOUT * DIN) / 4;
  wround_k<<<(nB4 + 255) / 256, 256, 0, stream>>>(Bre, Brw, nB4,  1.0f);
  wround_k<<<(nB4 + 255) / 256, 256, 0, stream>>>(Bim, Biw, nB4,  1.0f);
  wround_k<<<(nC4 + 255) / 256, 256, 0, stream>>>(Cre, Crw, nC4,  1.0f);
  wround_k<<<(nC4 + 255) / 256, 256, 0, stream>>>(Cim, Ciw, nC4, -1.0f);
  wround_k<<<(nD4 + 255) / 256, 256, 0, stream>>>(Dm,  Dw,  nD4,  1.0f);

  if (full) {
    const int nX4 = (int)(XPLANE / 4);
    wsplit_k<<<(nX4 + 255) / 256, 256, 0, stream>>>(x, xh, xl, nX4);
    bu_mfma<true><<<1024, 512, 0, stream>>>(
        x, xh, xl, Brw, Biw, gamma, re_h, re_l, im_h, im_l);
  } else {
    bu_mfma<false><<<1024, 512, 0, stream>>>(
        x, xh, xl, Brw, Biw, gamma, re_h, re_l, im_h, im_l);
  }

  scan_partial<<<(BSZ * NC * NST) / 256, 256, 0, stream>>>(re_h, re_l, im_h, im_l, lam, carry);
  scan_carry<<<(BSZ * NST) / 256, 256, 0, stream>>>(carry, lamL);
  scan_final<<<(BSZ * NC * NST) / 256, 256, 0, stream>>>(re_h, re_l, im_h, im_l, lam, carry);

  if (full) {
    out_mfma<true><<<1024, 512, 0, stream>>>(
        re_h, re_l, im_h, im_l, x, xh, xl, Crw, Ciw, Dw, y);
  } else {
    out_mfma<false><<<1024, 512, 0, stream>>>(
        re_h, re_l, im_h, im_l, x, xh, xl, Crw, Ciw, Dw, y);
  }
}

// Round 11
// 520.984 us; speedup vs baseline: 1.2680x; 1.1219x over previous
//
#include <hip/hip_runtime.h>
#include <stdint.h>

// LRU forward: y = Re(scan(lam, gamma*(x@B^T)) @ C^T) + x @ D^T
// Round 11: T3 phase-split port (m201 shape). Each K-step = 4 row-phases
// {ds_read; barrier; lgkmcnt(0); sched_barrier; setprio(1); 8 MFMA; setprio(0);
// barrier}; staging issued at tile start into the just-freed dbuf half, counted
// vmcnt(4) (never 0 mid-loop). Else identical to round 10.

#define BSZ   8
#define TLEN  4096
#define DIN   1024
#define DOUT  1024
#define NST   512
#define M_TOT (BSZ * TLEN)   // 32768
#define NC    32
#define CL    128
#define PLA   4096           // A plane: 128 rows x 32 shorts (8 KB)
#define BUFS  16384          // shorts per buffer (32 KB): Ah@0, Al@4096, W@8192

typedef __attribute__((ext_vector_type(8))) short bf16x8;
typedef __attribute__((ext_vector_type(4))) float f32x4;

// ---- bf16 helpers -------------------------------------------------------------------------
__device__ __forceinline__ float s2f(short s) {
  unsigned v = ((unsigned)(unsigned short)s) << 16;
  return __builtin_bit_cast(float, v);
}
__device__ __forceinline__ short f2s_rne(float f) {
  unsigned u = __builtin_bit_cast(unsigned, f);
  unsigned r = (u + 0x7FFFu + ((u >> 16) & 1u)) >> 16;
  return (short)r;
}
// h = truncated-bf16(f) (residual exactly representable), l = RNE(f - h)
__device__ __forceinline__ void split(float f, short& h, short& l) {
  const unsigned u = __builtin_bit_cast(unsigned, f);
  h = (short)(u >> 16);
  const float fh = __builtin_bit_cast(float, u & 0xFFFF0000u);
  l = f2s_rne(f - fh);
}
__device__ __forceinline__ void split8(const float4 v0, const float4 v1,
                                       bf16x8& hv, bf16x8& lv) {
  const float f[8] = {v0.x, v0.y, v0.z, v0.w, v1.x, v1.y, v1.z, v1.w};
  #pragma unroll
  for (int j = 0; j < 8; ++j) { short hh, ll; split(f[j], hh, ll); hv[j] = hh; lv[j] = ll; }
}

// ---- async global->LDS, 16B per lane ------------------------------------------------------
__device__ __forceinline__ void gload16(const short* g, short* l) {
  __builtin_amdgcn_global_load_lds(
      (const __attribute__((address_space(1))) void*)g,
      (__attribute__((address_space(3))) void*)l, 16, 0, 0);
}

// Quad-XOR swizzle (verified r5-r10: 0 conflicts): data quad q of row r -> slot q^((r>>1)&3);
// DMA dest linear, SOURCE pre-permuted, ds_read applies the XOR.

// ---- stage one K-tile (32 chunks of 16 rows x 32 shorts); wave w -> chunks 4w..4w+3 -------
// chunks 0-7: Ah rows, 8-15: Al rows, 16-31: W rows. 4 DMA loads per wave.
__device__ __forceinline__ void stage_cx(
    const short* __restrict__ Ahg, const short* __restrict__ Alg,
    const short* __restrict__ Wg, const int lda, const int ldb,
    const int m0, const int n0, const int k0,
    short* lbuf, const int w, const int lane)
{
  const int q  = (lane & 3) ^ ((lane >> 3) & 3);
  const int gr = lane >> 2;
  #pragma unroll
  for (int j = 0; j < 4; ++j) {
    const int ch = w * 4 + j;
    const short* g;
    int r0, ld;
    if (ch < 8)       { g = Ahg; r0 = m0 + ch * 16;        ld = lda; }
    else if (ch < 16) { g = Alg; r0 = m0 + (ch - 8) * 16;  ld = lda; }
    else              { g = Wg;  r0 = n0 + (ch - 16) * 16; ld = ldb; }
    gload16(g + (size_t)(r0 + gr) * ld + k0 + q * 8, lbuf + ch * 512);
  }
}

// ---- 4-phase pipelined GEMM: 8 waves, wave tile 64x64, 2 MFMA/product ---------------------
template<int NT>
__device__ __forceinline__ void gemm_pl(
    const short* __restrict__ Aph, const short* __restrict__ Apl,
    const short* __restrict__ Wp, const int lda, const int ldb,
    const int m0, const int n0, const int tid,
    f32x4 (&acc)[4][4], short* lds)
{
  const int lane = tid & 63, w = tid >> 6, wm = w >> 2, wn = w & 3;
  const int lr = lane & 15, kg = lane >> 4;
  const int qo = (kg ^ ((lr >> 1) & 3)) * 8;

  stage_cx(Aph, Apl, Wp, lda, ldb, m0, n0, 0, lds, w, lane);   // tile 0 -> buf0

  for (int k = 0; k < NT; ++k) {
    short* cur = lds + (k & 1) * BUFS;
    // Issue tile k+1 into the buffer freed by tile k-1 (all its reads completed
    // before the previous iteration's trailing barrier), then drain tile k only.
    if (k + 1 < NT) {
      stage_cx(Aph, Apl, Wp, lda, ldb, m0, n0, (k + 1) * 32,
               lds + ((k + 1) & 1) * BUFS, w, lane);
      asm volatile("s_waitcnt vmcnt(4)" ::: "memory");
    } else {
      asm volatile("s_waitcnt vmcnt(0)" ::: "memory");
    }
    __builtin_amdgcn_s_barrier();            // tile-k DMA visible to all waves

    bf16x8 bw[4];
    #pragma unroll
    for (int mi = 0; mi < 4; ++mi) {         // 4 phases, one acc-row each
      if (mi == 0) {                         // P0 additionally reads all 4 W frags
        #pragma unroll
        for (int ni = 0; ni < 4; ++ni)
          bw[ni] = *(const bf16x8*)&cur[2 * PLA + (wn * 64 + ni * 16 + lr) * 32 + qo];
      }
      const int ro = (wm * 64 + mi * 16 + lr) * 32 + qo;
      const bf16x8 ah = *(const bf16x8*)&cur[ro];
      const bf16x8 al = *(const bf16x8*)&cur[PLA + ro];
      __builtin_amdgcn_s_barrier();          // phase start: all waves issued reads
      asm volatile("s_waitcnt lgkmcnt(0)" ::: "memory");
      __builtin_amdgcn_sched_barrier(0);     // rule-18 fence: keep MFMA after the wait
      __builtin_amdgcn_s_setprio(1);
      #pragma unroll
      for (int ni = 0; ni < 4; ++ni) {
        acc[mi][ni] = __builtin_amdgcn_mfma_f32_16x16x32_bf16(ah, bw[ni], acc[mi][ni], 0, 0, 0);
        acc[mi][ni] = __builtin_amdgcn_mfma_f32_16x16x32_bf16(al, bw[ni], acc[mi][ni], 0, 0, 0);
      }
      __builtin_amdgcn_s_setprio(0);
      __builtin_amdgcn_s_barrier();          // phase end
    }
  }
}

// ---- fallback GEMM (x fp32 row-major, reg-split; W single plane), 512 threads -------------
__device__ __forceinline__ void gemm_fb(
    const float* __restrict__ Af, const short* __restrict__ Wp,
    const int lda, const int ldb, const int K, const int m0, const int n0, const int tid,
    f32x4 (&acc)[4][4], short* lds)        // single buffer: Ah@0, Al@PLA, W@2*PLA
{
  const int lane = tid & 63, w = tid >> 6, wm = w >> 2, wn = w & 3;
  const int r = tid & 127, e = (tid >> 7) & 3;   // row, k-quad
  short *LAh = lds, *LAl = lds + PLA, *LB = lds + 2 * PLA;
  float4 pa[2];
  {
    const float* p = Af + (size_t)(m0 + r) * lda + e * 8;
    pa[0] = *(const float4*)(p);
    pa[1] = *(const float4*)(p + 4);
  }
  for (int k0 = 0; k0 < K; k0 += 32) {
    __syncthreads();
    {
      bf16x8 hv, lv;
      split8(pa[0], pa[1], hv, lv);
      const int f = (r >> 1) & 3;
      const int qq = (e ^ f) * 8;
      *(bf16x8*)&LAh[r * 32 + qq] = hv;
      *(bf16x8*)&LAl[r * 32 + qq] = lv;
    }
    {
      const int q = (lane & 3) ^ ((lane >> 3) & 3);
      const int gr = lane >> 2;
      #pragma unroll
      for (int i = 0; i < 2; ++i)
        gload16(Wp + (size_t)(n0 + (2 * w + i) * 16 + gr) * ldb + k0 + q * 8,
                LB + (2 * w + i) * 512);
    }
    __syncthreads();
    if (k0 + 32 < K) {
      const float* p = Af + (size_t)(m0 + r) * lda + (k0 + 32) + e * 8;
      pa[0] = *(const float4*)(p);
      pa[1] = *(const float4*)(p + 4);
    }
    const int lr = lane & 15, kg = lane >> 4;
    const int qo = (kg ^ ((lr >> 1) & 3)) * 8;
    bf16x8 ah[4], al[4], bw[4];
    #pragma unroll
    for (int mi = 0; mi < 4; ++mi) {
      const int ro = (wm * 64 + mi * 16 + lr) * 32 + qo;
      ah[mi] = *(const bf16x8*)&LAh[ro];
      al[mi] = *(const bf16x8*)&LAl[ro];
    }
    #pragma unroll
    for (int ni = 0; ni < 4; ++ni)
      bw[ni] = *(const bf16x8*)&LB[(wn * 64 + ni * 16 + lr) * 32 + qo];
    #pragma unroll
    for (int ni = 0; ni < 4; ++ni)
      #pragma unroll
      for (int mi = 0; mi < 4; ++mi) {
        acc[mi][ni] = __builtin_amdgcn_mfma_f32_16x16x32_bf16(ah[mi], bw[ni], acc[mi][ni], 0, 0, 0);
        acc[mi][ni] = __builtin_amdgcn_mfma_f32_16x16x32_bf16(al[mi], bw[ni], acc[mi][ni], 0, 0, 0);
      }
  }
  __syncthreads();
}

// ---- XCD-locality block mapping: grid 1024 = 256 m-blocks x 4 n-blocks --------------------
__device__ __forceinline__ void map_mn4(const int bid, int& mb, int& nb) {
  const int xcd = bid & 7;
  const int j   = bid >> 3;       // 0..127
  mb = xcd * 32 + (j >> 2);       // 0..255
  nb = j & 3;                     // 0..3
}

// ---- weight pre-round (single RNE, signed) and x pre-split --------------------------------
__global__ __launch_bounds__(256) void wround_k(const float* __restrict__ src,
    short* __restrict__ h, const int n4, const float sgn)
{
  const int i = blockIdx.x * 256 + threadIdx.x;
  if (i >= n4) return;
  const float4 v = ((const float4*)src)[i];
  short4 hv;
  hv.x = f2s_rne(sgn * v.x); hv.y = f2s_rne(sgn * v.y);
  hv.z = f2s_rne(sgn * v.z); hv.w = f2s_rne(sgn * v.w);
  ((short4*)h)[i] = hv;
}
__global__ __launch_bounds__(256) void wsplit_k(const float* __restrict__ src,
    short* __restrict__ h, short* __restrict__ l, const int n4)
{
  const int i = blockIdx.x * 256 + threadIdx.x;
  if (i >= n4) return;
  const float4 v = ((const float4*)src)[i];
  short4 hv, lv;
  split(v.x, hv.x, lv.x); split(v.y, hv.y, lv.y);
  split(v.z, hv.z, lv.z); split(v.w, hv.w, lv.w);
  ((short4*)h)[i] = hv;
  ((short4*)l)[i] = lv;
}

// ---- kernel 1: Bu planes (row-major) = split(gamma * (x @ [Bre|Bim]^T)) -------------------
template<bool XAG>
__global__ __launch_bounds__(512, 4) void bu_mfma(
    const float* __restrict__ x, const short* __restrict__ xh, const short* __restrict__ xl,
    const short* __restrict__ Brw, const short* __restrict__ Biw,
    const float* __restrict__ gamma,
    short* __restrict__ re_h, short* __restrict__ re_l,
    short* __restrict__ im_h, short* __restrict__ im_l)
{
  __shared__ short lds[2 * BUFS];          // 64 KB
  f32x4 acc[4][4] = {};
  const int tid = threadIdx.x;
  int mb, nbk;
  map_mn4(blockIdx.x, mb, nbk);
  const int m0  = mb * 128;
  const int n0s = nbk * 256;               // 0,256 -> re; 512,768 -> im
  const bool re = (n0s < NST);
  const int nb0 = n0s & (NST - 1);
  const short* Bw = re ? Brw : Biw;

  if constexpr (XAG)
    gemm_pl<32>(xh, xl, Bw, DIN, DIN, m0, nb0, tid, acc, lds);
  else
    gemm_fb(x, Bw, DIN, DIN, DIN, m0, nb0, tid, acc, lds);

  short* Hp = re ? re_h : im_h;
  short* Lp = re ? re_l : im_l;
  const int lane = tid & 63, w = tid >> 6, wm = w >> 2, wn = w & 3;
  const int lr = lane & 15, lq = lane >> 4;
  #pragma unroll
  for (int ni = 0; ni < 4; ++ni) {
    const int nb = nb0 + wn * 64 + ni * 16 + lr;
    const float g = gamma[nb];
    #pragma unroll
    for (int mi = 0; mi < 4; ++mi)
      #pragma unroll
      for (int j = 0; j < 4; ++j) {
        const size_t m = (size_t)m0 + wm * 64 + mi * 16 + lq * 4 + j;
        short hh, ll;
        split(acc[mi][ni][j] * g, hh, ll);
        Hp[m * NST + nb] = hh;
        Lp[m * NST + nb] = ll;
      }
  }
}

// ---- scan params --------------------------------------------------------------------------
__global__ void params_k(const float* __restrict__ nulog, const float* __restrict__ thlog,
                         const float* __restrict__ glog,
                         float2* __restrict__ lam, float2* __restrict__ lamL,
                         float* __restrict__ gamma)
{
  const int n = blockIdx.x * 256 + threadIdx.x;
  if (n >= NST) return;
  const float nu = expf(nulog[n]);
  const float th = expf(thlog[n]);
  const float mod = expf(-nu);
  float s, c;
  sincosf(th, &s, &c);
  lam[n] = make_float2(mod * c, mod * s);
  const float modL = expf(-(float)CL * nu);
  float sL, cL;
  sincosf((float)CL * th, &sL, &cL);
  lamL[n] = make_float2(modL * cL, modL * sL);
  gamma[n] = expf(glog[n]);
}

// ---- scan phase 1 -------------------------------------------------------------------------
__global__ __launch_bounds__(256) void scan_partial(
    const short* __restrict__ re_h, const short* __restrict__ re_l,
    const short* __restrict__ im_h, const short* __restrict__ im_l,
    const float2* __restrict__ lam, float2* __restrict__ carry)
{
  const int g = blockIdx.x * 256 + threadIdx.x;
  const int n = g & (NST - 1);
  const int c = (g >> 9) & (NC - 1);
  const int b = g >> 14;
  const float2 L = lam[n];
  size_t idx = ((size_t)b * TLEN + (size_t)c * CL) * NST + n;
  float sr = 0.f, si = 0.f;
  #pragma unroll 4
  for (int t = 0; t < CL; ++t, idx += NST) {
    const float br = s2f(re_h[idx]) + s2f(re_l[idx]);
    const float bi = s2f(im_h[idx]) + s2f(im_l[idx]);
    const float nr = fmaf(L.x, sr, fmaf(-L.y, si, br));
    const float ni = fmaf(L.x, si, fmaf( L.y, sr, bi));
    sr = nr; si = ni;
  }
  carry[(size_t)(b * NC + c) * NST + n] = make_float2(sr, si);
}

// ---- scan phase 2 -------------------------------------------------------------------------
__global__ __launch_bounds__(256) void scan_carry(
    float2* __restrict__ carry, const float2* __restrict__ lamL)
{
  const int g = blockIdx.x * 256 + threadIdx.x;
  const int n = g & (NST - 1);
  const int b = g >> 9;
  const float2 P = lamL[n];
  float sr = 0.f, si = 0.f;
  for (int c = 0; c < NC; ++c) {
    const size_t idx = (size_t)(b * NC + c) * NST + n;
    const float2 v = carry[idx];
    carry[idx] = make_float2(sr, si);
    const float nr = fmaf(P.x, sr, fmaf(-P.y, si, v.x));
    const float ni = fmaf(P.x, si, fmaf( P.y, sr, v.y));
    sr = nr; si = ni;
  }
}

// ---- scan phase 3 -------------------------------------------------------------------------
__global__ __launch_bounds__(256) void scan_final(
    short* __restrict__ re_h, short* __restrict__ re_l,
    short* __restrict__ im_h, short* __restrict__ im_l,
    const float2* __restrict__ lam, const float2* __restrict__ carry)
{
  const int g = blockIdx.x * 256 + threadIdx.x;
  const int n = g & (NST - 1);
  const int c = (g >> 9) & (NC - 1);
  const int b = g >> 14;
  const float2 L = lam[n];
  const float2 ci = carry[(size_t)(b * NC + c) * NST + n];
  size_t idx = ((size_t)b * TLEN + (size_t)c * CL) * NST + n;
  float sr = ci.x, si = ci.y;
  #pragma unroll 4
  for (int t = 0; t < CL; ++t, idx += NST) {
    const float br = s2f(re_h[idx]) + s2f(re_l[idx]);
    const float bi = s2f(im_h[idx]) + s2f(im_l[idx]);
    const float nr = fmaf(L.x, sr, fmaf(-L.y, si, br));
    const float ni = fmaf(L.x, si, fmaf( L.y, sr, bi));
    sr = nr; si = ni;
    short hh, ll;
    split(sr, hh, ll); re_h[idx] = hh; re_l[idx] = ll;
    split(si, hh, ll); im_h[idx] = hh; im_l[idx] = ll;
  }
}

// ---- kernel 5: y = st_re@Cre^T - st_im@Cim^T + x@D^T --------------------------------------
template<bool XAG>
__global__ __launch_bounds__(512, 4) void out_mfma(
    const short* __restrict__ re_h, const short* __restrict__ re_l,
    const short* __restrict__ im_h, const short* __restrict__ im_l,
    const float* __restrict__ x, const short* __restrict__ xh, const short* __restrict__ xl,
    const short* __restrict__ Crw, const short* __restrict__ Ciw,  // Cim pre-negated
    const short* __restrict__ Dw,
    float* __restrict__ y)
{
  __shared__ short lds[2 * BUFS];          // 64 KB
  f32x4 acc[4][4] = {};
  const int tid = threadIdx.x;
  int mb, nbk;
  map_mn4(blockIdx.x, mb, nbk);
  const int m0 = mb * 128;
  const int o0 = nbk * 256;

  gemm_pl<16>(re_h, re_l, Crw, NST, NST, m0, o0, tid, acc, lds);
  gemm_pl<16>(im_h, im_l, Ciw, NST, NST, m0, o0, tid, acc, lds);
  if constexpr (XAG)
    gemm_pl<32>(xh, xl, Dw, DIN, DIN, m0, o0, tid, acc, lds);
  else
    gemm_fb(x, Dw, DIN, DIN, DIN, m0, o0, tid, acc, lds);

  const int lane = tid & 63, w = tid >> 6, wm = w >> 2, wn = w & 3;
  const int lr = lane & 15, lq = lane >> 4;
  #pragma unroll
  for (int mi = 0; mi < 4; ++mi)
    #pragma unroll
    for (int j = 0; j < 4; ++j) {
      const size_t m = (size_t)m0 + wm * 64 + mi * 16 + lq * 4 + j;
      #pragma unroll
      for (int ni = 0; ni < 4; ++ni)
        y[m * DOUT + o0 + wn * 64 + ni * 16 + lr] = acc[mi][ni][j];
    }
}

// ---- host launch --------------------------------------------------------------------------
extern "C" void kernel_launch(void* const* d_in, const int* in_sizes, int n_in,
                              void* d_out, int out_size, void* d_ws, size_t ws_size,
                              hipStream_t stream)
{
  (void)in_sizes; (void)n_in; (void)out_size;
  const float* x     = (const float*)d_in[0];
  const float* nulog = (const float*)d_in[1];
  const float* thlog = (const float*)d_in[2];
  const float* glog  = (const float*)d_in[3];
  const float* Bre   = (const float*)d_in[4];
  const float* Bim   = (const float*)d_in[5];
  const float* Cre   = (const float*)d_in[6];
  const float* Cim   = (const float*)d_in[7];
  const float* Dm    = (const float*)d_in[8];
  float* y = (float*)d_out;

  // ws layout: 4 state planes | carry | lam | lamL | gamma | weight planes | [x planes]
  const size_t PLANE  = (size_t)M_TOT * NST;
  const size_t XPLANE = (size_t)M_TOT * DIN;
  short*  re_h  = (short*)d_ws;
  short*  re_l  = re_h + PLANE;
  short*  im_h  = re_l + PLANE;
  short*  im_l  = im_h + PLANE;
  float2* carry = (float2*)(im_l + PLANE);
  float2* lam   = carry + (size_t)BSZ * NC * NST;
  float2* lamL  = lam + NST;
  float*  gamma = (float*)(lamL + NST);

  char* wp = (char*)(gamma + NST);
  wp = (char*)(((uintptr_t)wp + 255) & ~(uintptr_t)255);
  short* Brw = (short*)wp;                          // single RNE planes
  short* Biw = Brw + (size_t)NST * DIN;
  short* Crw = Biw + (size_t)NST * DIN;
  short* Ciw = Crw + (size_t)DOUT * NST;            // pre-negated
  short* Dw  = Ciw + (size_t)DOUT * NST;
  short* xh  = Dw  + (size_t)DOUT * DIN;            // x hi/lo (row-major)
  short* xl  = xh + XPLANE;
  const size_t needed_full = (size_t)((char*)(xl + XPLANE) - (char*)d_ws);
  const bool full = (ws_size >= needed_full);

  params_k<<<2, 256, 0, stream>>>(nulog, thlog, glog, lam, lamL, gamma);

  const int nB4 = (NST * DIN) / 4, nC4 = (DOUT * NST) / 4, nD4 = (DOUT * DIN) / 4;
  wround_k<<<(nB4 + 255) / 256, 256, 0, stream>>>(Bre, Brw, nB4,  1.0f);
  wround_k<<<(nB4 + 255) / 256, 256, 0, stream>>>(Bim, Biw, nB4,  1.0f);
  wround_k<<<(nC4 + 255) / 256, 256, 0, stream>>>(Cre, Crw, nC4,  1.0f);
  wround_k<<<(nC4 + 255) / 256, 256, 0, stream>>>(Cim, Ciw, nC4, -1.0f);
  wround_k<<<(nD4 + 255) / 256, 256, 0, stream>>>(Dm,  Dw,  nD4,  1.0f);

  if (full) {
    const int nX4 = (int)(XPLANE / 4);
    wsplit_k<<<(nX4 + 255) / 256, 256, 0, stream>>>(x, xh, xl, nX4);
    bu_mfma<true><<<1024, 512, 0, stream>>>(
        x, xh, xl, Brw, Biw, gamma, re_h, re_l, im_h, im_l);
  } else {
    bu_mfma<false><<<1024, 512, 0, stream>>>(
        x, xh, xl, Brw, Biw, gamma, re_h, re_l, im_h, im_l);
  }

  scan_partial<<<(BSZ * NC * NST) / 256, 256, 0, stream>>>(re_h, re_l, im_h, im_l, lam, carry);
  scan_carry<<<(BSZ * NST) / 256, 256, 0, stream>>>(carry, lamL);
  scan_final<<<(BSZ * NC * NST) / 256, 256, 0, stream>>>(re_h, re_l, im_h, im_l, lam, carry);

  if (full) {
    out_mfma<true><<<1024, 512, 0, stream>>>(
        re_h, re_l, im_h, im_l, x, xh, xl, Crw, Ciw, Dw, y);
  } else {
    out_mfma<false><<<1024, 512, 0, stream>>>(
        re_h, re_l, im_h, im_l, x, xh, xl, Crw, Ciw, Dw, y);
  }
}

// Round 12
// 376.030 us; speedup vs baseline: 1.7567x; 1.3855x over previous
//
#include <hip/hip_runtime.h>
#include <stdint.h>

// LRU forward: y = Re(scan(lam, gamma*(x@B^T)) @ C^T) + x @ D^T
// Round 12: single-bf16 A operands for GEMMs (states, x) -> 1 MFMA/product
// (halves MFMA count). Bu stays hi/lo (scan input precision preserved).
// 2-phase K-step (8 MFMA each), vmcnt(3), dbuf 48KB. Scans vectorized 2-n/thread;
// scan_final writes single-plane states.

#define BSZ   8
#define TLEN  4096
#define DIN   1024
#define DOUT  1024
#define NST   512
#define M_TOT (BSZ * TLEN)   // 32768
#define NC    32
#define CL    128
#define PLA   4096           // A plane: 128 rows x 32 shorts (8 KB)
#define BUFS  12288          // shorts per buffer (24 KB): A@0, W@4096

typedef __attribute__((ext_vector_type(8))) short bf16x8;
typedef __attribute__((ext_vector_type(4))) float f32x4;

// ---- bf16 helpers -------------------------------------------------------------------------
__device__ __forceinline__ float s2f(short s) {
  unsigned v = ((unsigned)(unsigned short)s) << 16;
  return __builtin_bit_cast(float, v);
}
__device__ __forceinline__ short f2s_rne(float f) {
  unsigned u = __builtin_bit_cast(unsigned, f);
  unsigned r = (u + 0x7FFFu + ((u >> 16) & 1u)) >> 16;
  return (short)r;
}
// h = truncated-bf16(f) (residual exactly representable), l = RNE(f - h)
__device__ __forceinline__ void split(float f, short& h, short& l) {
  const unsigned u = __builtin_bit_cast(unsigned, f);
  h = (short)(u >> 16);
  const float fh = __builtin_bit_cast(float, u & 0xFFFF0000u);
  l = f2s_rne(f - fh);
}
__device__ __forceinline__ void round8(const float4 v0, const float4 v1, bf16x8& hv) {
  const float f[8] = {v0.x, v0.y, v0.z, v0.w, v1.x, v1.y, v1.z, v1.w};
  #pragma unroll
  for (int j = 0; j < 8; ++j) hv[j] = f2s_rne(f[j]);
}

// ---- async global->LDS, 16B per lane ------------------------------------------------------
__device__ __forceinline__ void gload16(const short* g, short* l) {
  __builtin_amdgcn_global_load_lds(
      (const __attribute__((address_space(1))) void*)g,
      (__attribute__((address_space(3))) void*)l, 16, 0, 0);
}

// Quad-XOR swizzle (verified r5-r11: 0 conflicts): data quad q of row r -> slot q^((r>>1)&3);
// DMA dest linear, SOURCE pre-permuted, ds_read applies the XOR.

// ---- stage one K-tile (24 chunks of 16 rows x 32 shorts); wave w -> chunks 3w..3w+2 -------
// chunks 0-7: A rows (m0,lda); chunks 8-23: W rows (n0,ldb). 3 DMA loads per wave.
__device__ __forceinline__ void stage_cx(
    const short* __restrict__ Ag, const short* __restrict__ Wg,
    const int lda, const int ldb, const int m0, const int n0, const int k0,
    short* lbuf, const int w, const int lane)
{
  const int q  = (lane & 3) ^ ((lane >> 3) & 3);
  const int gr = lane >> 2;
  #pragma unroll
  for (int j = 0; j < 3; ++j) {
    const int ch = w * 3 + j;
    const short* g;
    int r0, ld, dst;
    if (ch < 8) { g = Ag; r0 = m0 + ch * 16;        ld = lda; dst = ch * 512; }
    else        { g = Wg; r0 = n0 + (ch - 8) * 16;  ld = ldb; dst = PLA + (ch - 8) * 512; }
    gload16(g + (size_t)(r0 + gr) * ld + k0 + q * 8, lbuf + dst);
  }
}

// ---- 2-phase pipelined GEMM: 8 waves, wave tile 64x64, 1 MFMA/product ---------------------
template<int NT>
__device__ __forceinline__ void gemm_pl(
    const short* __restrict__ Ap, const short* __restrict__ Wp,
    const int lda, const int ldb, const int m0, const int n0, const int tid,
    f32x4 (&acc)[4][4], short* lds)
{
  const int lane = tid & 63, w = tid >> 6, wm = w >> 2, wn = w & 3;
  const int lr = lane & 15, kg = lane >> 4;
  const int qo = (kg ^ ((lr >> 1) & 3)) * 8;

  stage_cx(Ap, Wp, lda, ldb, m0, n0, 0, lds, w, lane);   // tile 0 -> buf0

  for (int k = 0; k < NT; ++k) {
    short* cur = lds + (k & 1) * BUFS;
    if (k + 1 < NT) {                        // issue k+1 into freed half; drain k only
      stage_cx(Ap, Wp, lda, ldb, m0, n0, (k + 1) * 32,
               lds + ((k + 1) & 1) * BUFS, w, lane);
      asm volatile("s_waitcnt vmcnt(3)" ::: "memory");
    } else {
      asm volatile("s_waitcnt vmcnt(0)" ::: "memory");
    }
    __builtin_amdgcn_s_barrier();            // tile-k DMA visible to all waves

    bf16x8 bw[4];
    #pragma unroll
    for (int ph = 0; ph < 2; ++ph) {         // 2 phases, 2 acc-rows each
      if (ph == 0) {
        #pragma unroll
        for (int ni = 0; ni < 4; ++ni)
          bw[ni] = *(const bf16x8*)&cur[PLA + (wn * 64 + ni * 16 + lr) * 32 + qo];
      }
      const int mi0 = ph * 2;
      const bf16x8 a0 = *(const bf16x8*)&cur[(wm * 64 + mi0 * 16 + lr) * 32 + qo];
      const bf16x8 a1 = *(const bf16x8*)&cur[(wm * 64 + (mi0 + 1) * 16 + lr) * 32 + qo];
      __builtin_amdgcn_s_barrier();          // phase start: all waves issued reads
      asm volatile("s_waitcnt lgkmcnt(0)" ::: "memory");
      __builtin_amdgcn_sched_barrier(0);     // rule-18 fence
      __builtin_amdgcn_s_setprio(1);
      #pragma unroll
      for (int ni = 0; ni < 4; ++ni) {
        acc[mi0][ni]     = __builtin_amdgcn_mfma_f32_16x16x32_bf16(a0, bw[ni], acc[mi0][ni], 0, 0, 0);
        acc[mi0 + 1][ni] = __builtin_amdgcn_mfma_f32_16x16x32_bf16(a1, bw[ni], acc[mi0 + 1][ni], 0, 0, 0);
      }
      __builtin_amdgcn_s_setprio(0);
      __builtin_amdgcn_s_barrier();          // phase end
    }
  }
}

// ---- fallback GEMM (A fp32 row-major, reg-round; W single plane), 512 threads -------------
__device__ __forceinline__ void gemm_fb(
    const float* __restrict__ Af, const short* __restrict__ Wp,
    const int lda, const int ldb, const int K, const int m0, const int n0, const int tid,
    f32x4 (&acc)[4][4], short* lds)          // single buffer: A@0, W@PLA
{
  const int lane = tid & 63, w = tid >> 6, wm = w >> 2, wn = w & 3;
  const int r = tid & 127, e = (tid >> 7) & 3;   // row, k-quad
  float4 pa[2];
  {
    const float* p = Af + (size_t)(m0 + r) * lda + e * 8;
    pa[0] = *(const float4*)(p);
    pa[1] = *(const float4*)(p + 4);
  }
  for (int k0 = 0; k0 < K; k0 += 32) {
    __syncthreads();
    {
      bf16x8 hv;
      round8(pa[0], pa[1], hv);
      const int f = (r >> 1) & 3;
      *(bf16x8*)&lds[r * 32 + ((e ^ f) * 8)] = hv;
    }
    {
      const int q = (lane & 3) ^ ((lane >> 3) & 3);
      const int gr = lane >> 2;
      #pragma unroll
      for (int i = 0; i < 2; ++i)
        gload16(Wp + (size_t)(n0 + (2 * w + i) * 16 + gr) * ldb + k0 + q * 8,
                lds + PLA + (2 * w + i) * 512);
    }
    __syncthreads();
    if (k0 + 32 < K) {
      const float* p = Af + (size_t)(m0 + r) * lda + (k0 + 32) + e * 8;
      pa[0] = *(const float4*)(p);
      pa[1] = *(const float4*)(p + 4);
    }
    const int lr = lane & 15, kg = lane >> 4;
    const int qo = (kg ^ ((lr >> 1) & 3)) * 8;
    bf16x8 aw[4], bw[4];
    #pragma unroll
    for (int mi = 0; mi < 4; ++mi)
      aw[mi] = *(const bf16x8*)&lds[(wm * 64 + mi * 16 + lr) * 32 + qo];
    #pragma unroll
    for (int ni = 0; ni < 4; ++ni)
      bw[ni] = *(const bf16x8*)&lds[PLA + (wn * 64 + ni * 16 + lr) * 32 + qo];
    #pragma unroll
    for (int ni = 0; ni < 4; ++ni)
      #pragma unroll
      for (int mi = 0; mi < 4; ++mi)
        acc[mi][ni] = __builtin_amdgcn_mfma_f32_16x16x32_bf16(aw[mi], bw[ni], acc[mi][ni], 0, 0, 0);
  }
  __syncthreads();
}

// ---- XCD-locality block mapping: grid 1024 = 256 m-blocks x 4 n-blocks --------------------
__device__ __forceinline__ void map_mn4(const int bid, int& mb, int& nb) {
  const int xcd = bid & 7;
  const int j   = bid >> 3;       // 0..127
  mb = xcd * 32 + (j >> 2);       // 0..255
  nb = j & 3;                     // 0..3
}

// ---- weight/x pre-round (single RNE, signed) ----------------------------------------------
__global__ __launch_bounds__(256) void wround_k(const float* __restrict__ src,
    short* __restrict__ h, const int n4, const float sgn)
{
  const int i = blockIdx.x * 256 + threadIdx.x;
  if (i >= n4) return;
  const float4 v = ((const float4*)src)[i];
  short4 hv;
  hv.x = f2s_rne(sgn * v.x); hv.y = f2s_rne(sgn * v.y);
  hv.z = f2s_rne(sgn * v.z); hv.w = f2s_rne(sgn * v.w);
  ((short4*)h)[i] = hv;
}

// ---- kernel 1: Bu planes (hi/lo, row-major) = split(gamma * (x @ [Bre|Bim]^T)) ------------
template<bool XAG>
__global__ __launch_bounds__(512, 4) void bu_mfma(
    const float* __restrict__ x, const short* __restrict__ xw,
    const short* __restrict__ Brw, const short* __restrict__ Biw,
    const float* __restrict__ gamma,
    short* __restrict__ re_h, short* __restrict__ re_l,
    short* __restrict__ im_h, short* __restrict__ im_l)
{
  __shared__ short lds[2 * BUFS];          // 48 KB
  f32x4 acc[4][4] = {};
  const int tid = threadIdx.x;
  int mb, nbk;
  map_mn4(blockIdx.x, mb, nbk);
  const int m0  = mb * 128;
  const int n0s = nbk * 256;               // 0,256 -> re; 512,768 -> im
  const bool re = (n0s < NST);
  const int nb0 = n0s & (NST - 1);
  const short* Bw = re ? Brw : Biw;

  if constexpr (XAG)
    gemm_pl<32>(xw, Bw, DIN, DIN, m0, nb0, tid, acc, lds);
  else
    gemm_fb(x, Bw, DIN, DIN, DIN, m0, nb0, tid, acc, lds);

  short* Hp = re ? re_h : im_h;
  short* Lp = re ? re_l : im_l;
  const int lane = tid & 63, w = tid >> 6, wm = w >> 2, wn = w & 3;
  const int lr = lane & 15, lq = lane >> 4;
  #pragma unroll
  for (int ni = 0; ni < 4; ++ni) {
    const int nb = nb0 + wn * 64 + ni * 16 + lr;
    const float g = gamma[nb];
    #pragma unroll
    for (int mi = 0; mi < 4; ++mi)
      #pragma unroll
      for (int j = 0; j < 4; ++j) {
        const size_t m = (size_t)m0 + wm * 64 + mi * 16 + lq * 4 + j;
        short hh, ll;
        split(acc[mi][ni][j] * g, hh, ll);
        Hp[m * NST + nb] = hh;
        Lp[m * NST + nb] = ll;
      }
  }
}

// ---- scan params --------------------------------------------------------------------------
__global__ void params_k(const float* __restrict__ nulog, const float* __restrict__ thlog,
                         const float* __restrict__ glog,
                         float2* __restrict__ lam, float2* __restrict__ lamL,
                         float* __restrict__ gamma)
{
  const int n = blockIdx.x * 256 + threadIdx.x;
  if (n >= NST) return;
  const float nu = expf(nulog[n]);
  const float th = expf(thlog[n]);
  const float mod = expf(-nu);
  float s, c;
  sincosf(th, &s, &c);
  lam[n] = make_float2(mod * c, mod * s);
  const float modL = expf(-(float)CL * nu);
  float sL, cL;
  sincosf((float)CL * th, &sL, &cL);
  lamL[n] = make_float2(modL * cL, modL * sL);
  gamma[n] = expf(glog[n]);
}

// ---- scan phase 1: 2-n per thread (short2), reads Bu hi/lo --------------------------------
__global__ __launch_bounds__(256) void scan_partial(
    const short* __restrict__ re_h, const short* __restrict__ re_l,
    const short* __restrict__ im_h, const short* __restrict__ im_l,
    const float2* __restrict__ lam, float2* __restrict__ carry)
{
  const int g = blockIdx.x * 256 + threadIdx.x;   // 65536 threads
  const int n2 = g & 255;
  const int c  = (g >> 8) & (NC - 1);
  const int b  = g >> 13;
  const int n  = n2 * 2;
  const float2 L0 = lam[n], L1 = lam[n + 1];
  const short2* RH = (const short2*)re_h;
  const short2* RL = (const short2*)re_l;
  const short2* IH = (const short2*)im_h;
  const short2* IL = (const short2*)im_l;
  size_t idx = ((size_t)b * TLEN + (size_t)c * CL) * (NST / 2) + n2;
  float sr0 = 0.f, si0 = 0.f, sr1 = 0.f, si1 = 0.f;
  #pragma unroll 4
  for (int t = 0; t < CL; ++t, idx += NST / 2) {
    const short2 vh = RH[idx], vl = RL[idx], wh = IH[idx], wl = IL[idx];
    const float br0 = s2f(vh.x) + s2f(vl.x), br1 = s2f(vh.y) + s2f(vl.y);
    const float bi0 = s2f(wh.x) + s2f(wl.x), bi1 = s2f(wh.y) + s2f(wl.y);
    float nr = fmaf(L0.x, sr0, fmaf(-L0.y, si0, br0));
    float ni = fmaf(L0.x, si0, fmaf( L0.y, sr0, bi0));
    sr0 = nr; si0 = ni;
    nr = fmaf(L1.x, sr1, fmaf(-L1.y, si1, br1));
    ni = fmaf(L1.x, si1, fmaf( L1.y, sr1, bi1));
    sr1 = nr; si1 = ni;
  }
  const size_t cb = (size_t)(b * NC + c) * NST + n;
  carry[cb]     = make_float2(sr0, si0);
  carry[cb + 1] = make_float2(sr1, si1);
}

// ---- scan phase 2 -------------------------------------------------------------------------
__global__ __launch_bounds__(256) void scan_carry(
    float2* __restrict__ carry, const float2* __restrict__ lamL)
{
  const int g = blockIdx.x * 256 + threadIdx.x;
  const int n = g & (NST - 1);
  const int b = g >> 9;
  const float2 P = lamL[n];
  float sr = 0.f, si = 0.f;
  for (int c = 0; c < NC; ++c) {
    const size_t idx = (size_t)(b * NC + c) * NST + n;
    const float2 v = carry[idx];
    carry[idx] = make_float2(sr, si);
    const float nr = fmaf(P.x, sr, fmaf(-P.y, si, v.x));
    const float ni = fmaf(P.x, si, fmaf( P.y, sr, v.y));
    sr = nr; si = ni;
  }
}

// ---- scan phase 3: reads Bu hi/lo, writes SINGLE-plane states into re_h/im_h --------------
__global__ __launch_bounds__(256) void scan_final(
    short* __restrict__ re_h, const short* __restrict__ re_l,
    short* __restrict__ im_h, const short* __restrict__ im_l,
    const float2* __restrict__ lam, const float2* __restrict__ carry)
{
  const int g = blockIdx.x * 256 + threadIdx.x;
  const int n2 = g & 255;
  const int c  = (g >> 8) & (NC - 1);
  const int b  = g >> 13;
  const int n  = n2 * 2;
  const float2 L0 = lam[n], L1 = lam[n + 1];
  const size_t cb = (size_t)(b * NC + c) * NST + n;
  const float2 ci0 = carry[cb], ci1 = carry[cb + 1];
  short2* RH = (short2*)re_h;
  const short2* RL = (const short2*)re_l;
  short2* IH = (short2*)im_h;
  const short2* IL = (const short2*)im_l;
  size_t idx = ((size_t)b * TLEN + (size_t)c * CL) * (NST / 2) + n2;
  float sr0 = ci0.x, si0 = ci0.y, sr1 = ci1.x, si1 = ci1.y;
  #pragma unroll 4
  for (int t = 0; t < CL; ++t, idx += NST / 2) {
    const short2 vh = RH[idx], vl = RL[idx], wh = IH[idx], wl = IL[idx];
    const float br0 = s2f(vh.x) + s2f(vl.x), br1 = s2f(vh.y) + s2f(vl.y);
    const float bi0 = s2f(wh.x) + s2f(wl.x), bi1 = s2f(wh.y) + s2f(wl.y);
    float nr = fmaf(L0.x, sr0, fmaf(-L0.y, si0, br0));
    float ni = fmaf(L0.x, si0, fmaf( L0.y, sr0, bi0));
    sr0 = nr; si0 = ni;
    nr = fmaf(L1.x, sr1, fmaf(-L1.y, si1, br1));
    ni = fmaf(L1.x, si1, fmaf( L1.y, sr1, bi1));
    sr1 = nr; si1 = ni;
    short2 so;
    so.x = f2s_rne(sr0); so.y = f2s_rne(sr1);
    RH[idx] = so;
    so.x = f2s_rne(si0); so.y = f2s_rne(si1);
    IH[idx] = so;
  }
}

// ---- kernel 5: y = st_re@Cre^T - st_im@Cim^T + x@D^T (all single-plane, 1 MFMA/prod) ------
template<bool XAG>
__global__ __launch_bounds__(512, 4) void out_mfma(
    const short* __restrict__ st_re, const short* __restrict__ st_im,
    const float* __restrict__ x, const short* __restrict__ xw,
    const short* __restrict__ Crw, const short* __restrict__ Ciw,  // Cim pre-negated
    const short* __restrict__ Dw,
    float* __restrict__ y)
{
  __shared__ short lds[2 * BUFS];          // 48 KB
  f32x4 acc[4][4] = {};
  const int tid = threadIdx.x;
  int mb, nbk;
  map_mn4(blockIdx.x, mb, nbk);
  const int m0 = mb * 128;
  const int o0 = nbk * 256;

  gemm_pl<16>(st_re, Crw, NST, NST, m0, o0, tid, acc, lds);
  gemm_pl<16>(st_im, Ciw, NST, NST, m0, o0, tid, acc, lds);
  if constexpr (XAG)
    gemm_pl<32>(xw, Dw, DIN, DIN, m0, o0, tid, acc, lds);
  else
    gemm_fb(x, Dw, DIN, DIN, DIN, m0, o0, tid, acc, lds);

  const int lane = tid & 63, w = tid >> 6, wm = w >> 2, wn = w & 3;
  const int lr = lane & 15, lq = lane >> 4;
  #pragma unroll
  for (int mi = 0; mi < 4; ++mi)
    #pragma unroll
    for (int j = 0; j < 4; ++j) {
      const size_t m = (size_t)m0 + wm * 64 + mi * 16 + lq * 4 + j;
      #pragma unroll
      for (int ni = 0; ni < 4; ++ni)
        y[m * DOUT + o0 + wn * 64 + ni * 16 + lr] = acc[mi][ni][j];
    }
}

// ---- host launch --------------------------------------------------------------------------
extern "C" void kernel_launch(void* const* d_in, const int* in_sizes, int n_in,
                              void* d_out, int out_size, void* d_ws, size_t ws_size,
                              hipStream_t stream)
{
  (void)in_sizes; (void)n_in; (void)out_size;
  const float* x     = (const float*)d_in[0];
  const float* nulog = (const float*)d_in[1];
  const float* thlog = (const float*)d_in[2];
  const float* glog  = (const float*)d_in[3];
  const float* Bre   = (const float*)d_in[4];
  const float* Bim   = (const float*)d_in[5];
  const float* Cre   = (const float*)d_in[6];
  const float* Cim   = (const float*)d_in[7];
  const float* Dm    = (const float*)d_in[8];
  float* y = (float*)d_out;

  // ws: Bu hi/lo planes (states overwrite hi) | carry | lam | lamL | gamma | weights | xw
  const size_t PLANE  = (size_t)M_TOT * NST;
  const size_t XPLANE = (size_t)M_TOT * DIN;
  short*  re_h  = (short*)d_ws;
  short*  re_l  = re_h + PLANE;
  short*  im_h  = re_l + PLANE;
  short*  im_l  = im_h + PLANE;
  float2* carry = (float2*)(im_l + PLANE);
  float2* lam   = carry + (size_t)BSZ * NC * NST;
  float2* lamL  = lam + NST;
  float*  gamma = (float*)(lamL + NST);

  char* wp = (char*)(gamma + NST);
  wp = (char*)(((uintptr_t)wp + 255) & ~(uintptr_t)255);
  short* Brw = (short*)wp;                          // single RNE planes
  short* Biw = Brw + (size_t)NST * DIN;
  short* Crw = Biw + (size_t)NST * DIN;
  short* Ciw = Crw + (size_t)DOUT * NST;            // pre-negated
  short* Dw  = Ciw + (size_t)DOUT * NST;
  short* xw  = Dw  + (size_t)DOUT * DIN;            // x single plane (row-major)
  const size_t needed_full = (size_t)((char*)(xw + XPLANE) - (char*)d_ws);
  const bool full = (ws_size >= needed_full);

  params_k<<<2, 256, 0, stream>>>(nulog, thlog, glog, lam, lamL, gamma);

  const int nB4 = (NST * DIN) / 4, nC4 = (DOUT * NST) / 4, nD4 = (DOUT * DIN) / 4;
  wround_k<<<(nB4 + 255) / 256, 256, 0, stream>>>(Bre, Brw, nB4,  1.0f);
  wround_k<<<(nB4 + 255) / 256, 256, 0, stream>>>(Bim, Biw, nB4,  1.0f);
  wround_k<<<(nC4 + 255) / 256, 256, 0, stream>>>(Cre, Crw, nC4,  1.0f);
  wround_k<<<(nC4 + 255) / 256, 256, 0, stream>>>(Cim, Ciw, nC4, -1.0f);
  wround_k<<<(nD4 + 255) / 256, 256, 0, stream>>>(Dm,  Dw,  nD4,  1.0f);

  if (full) {
    const int nX4 = (int)(XPLANE / 4);
    wround_k<<<(nX4 + 255) / 256, 256, 0, stream>>>(x, xw, nX4, 1.0f);
    bu_mfma<true><<<1024, 512, 0, stream>>>(
        x, xw, Brw, Biw, gamma, re_h, re_l, im_h, im_l);
  } else {
    bu_mfma<false><<<1024, 512, 0, stream>>>(
        x, xw, Brw, Biw, gamma, re_h, re_l, im_h, im_l);
  }

  scan_partial<<<(BSZ * NC * (NST / 2)) / 256, 256, 0, stream>>>(
      re_h, re_l, im_h, im_l, lam, carry);
  scan_carry<<<(BSZ * NST) / 256, 256, 0, stream>>>(carry, lamL);
  scan_final<<<(BSZ * NC * (NST / 2)) / 256, 256, 0, stream>>>(
      re_h, re_l, im_h, im_l, lam, carry);

  if (full) {
    out_mfma<true><<<1024, 512, 0, stream>>>(
        re_h, im_h, x, xw, Crw, Ciw, Dw, y);
  } else {
    out_mfma<false><<<1024, 512, 0, stream>>>(
        re_h, im_h, x, xw, Crw, Ciw, Dw, y);
  }
}